// Round 5
// baseline (2924.794 us; speedup 1.0000x reference)
//
#include <hip/hip_runtime.h>
#include <hip/hip_bf16.h>
#include <math.h>

typedef __bf16 bf16;
typedef __bf16 bf16x8 __attribute__((ext_vector_type(8)));
typedef __bf16 bf16x4 __attribute__((ext_vector_type(4)));
typedef float  f32x4  __attribute__((ext_vector_type(4)));

#define B_  4
#define N_  1024
#define C_  768
#define H_  12
#define HD_ 64
#define FF_ 3072
#define T_  (B_*N_)      // 4096 tokens
#define D_  12

// ---- async global->LDS, 16B per lane, wave-uniform LDS base ----
__device__ __forceinline__ void gld_lds16(const void* g, void* l) {
    __builtin_amdgcn_global_load_lds(
        (const __attribute__((address_space(1))) void*)g,
        (__attribute__((address_space(3))) void*)l, 16, 0, 0);
}

#define WAITV(N) asm volatile("s_waitcnt vmcnt(" #N ")" ::: "memory")
#define WAITL0() asm volatile("s_waitcnt lgkmcnt(0)" ::: "memory")

// ---- exact-enough GELU: A&S 7.1.26 erf, |err|<=1.5e-7 (invisible in bf16)
__device__ __forceinline__ float gelu_f(float v) {
    const float ax = fabsf(v) * 0.70710678118f;
    const float t  = __frcp_rn(1.0f + 0.3275911f * ax);
    float p = 1.061405429f;
    p = p * t - 1.453152027f;
    p = p * t + 1.421413741f;
    p = p * t - 0.284496736f;
    p = p * t + 0.254829592f;
    const float e = p * t * __expf(-ax * ax);
    const float erfv = (v >= 0.f) ? (1.0f - e) : (e - 1.0f);
    return 0.5f * v * (1.0f + erfv);
}

// =====================================================================
// GEMM:  out[M,N] = A[M,K] @ Bt[N,K]^T + bias
// MODE 0: store bf16   MODE 1: GELU then store bf16
// MODE 2: resid[M,N] (fp32) atomicAdd (split-K safe; bias only on z==0)
// bf16 path: 128x128 tile, BK=32, THREE LDS buffers (48 KB -> 3 blk/CU),
// depth-2 counted-vmcnt prefetch (T4): tiles t+1,t+2 stay in flight;
// raw s_barrier + s_waitcnt vmcnt(8) (4 loads/thread/tile) -- NEVER
// vmcnt(0) in the main loop. Round-4 lesson: __syncthreads drains
// vmcnt(0), making "prefetch" fake; this is the real pipeline.
// fp32 fallback: old single-buffer BK=64 loop (unused when ws fits).
// LDS XOR-swizzle both-sides; 1-D grid + XCD swizzle (T1).
// =====================================================================
template<typename WT, int MODE>
__global__ __launch_bounds__(256) void gemm_bt(
    const bf16* __restrict__ A, const WT* __restrict__ Bt,
    const float* __restrict__ bias, bf16* __restrict__ out,
    float* __restrict__ resid, int M, int N, int Kfull, int Ks)
{
    constexpr bool BF  = (sizeof(WT) == 2);
    constexpr int  BK  = BF ? 32 : 64;
    constexpr int  NBF = BF ? 3 : 1;
    __shared__ __align__(16) bf16 lA[NBF][128*BK];  // bf16: 3x8KB
    __shared__ __align__(16) WT   lB[NBF][128*BK];  // bf16: 3x8KB / f32: 32KB
    const int tid  = threadIdx.x;
    const int lane = tid & 63, wave = tid >> 6;
    const int lo = lane & 15, hi = lane >> 4;
    const int wm = wave & 1, wn = wave >> 1;

    // XCD swizzle: nblk % 8 == 0 for all call sites -> bijective
    const int nblk = gridDim.x;
    const int id2  = (blockIdx.x & 7) * (nblk >> 3) + (blockIdx.x >> 3);
    const int gx = M >> 7, gy = N >> 7;
    const int bx  = id2 % gx;
    const int byz = id2 / gx;
    const int by  = byz % gy;
    const int bz  = byz / gy;
    const int row0 = bx * 128, col0 = by * 128;
    const int k0base = bz * Ks;
    const int nt = Ks / BK;

    f32x4 acc[4][4];
#pragma unroll
    for (int i = 0; i < 4; i++)
#pragma unroll
        for (int j = 0; j < 4; j++) acc[i][j] = (f32x4){0.f, 0.f, 0.f, 0.f};

    if constexpr (BF) {
        // ---- staging: 2 A-chunks + 2 B-chunks per thread per tile ----
        auto stageA = [&](int t, int buf) {
#pragma unroll
            for (int r = 0; r < 2; ++r) {
                const int cb    = r * 256 + wave * 64;   // wave-uniform base
                const int chunk = cb + lane;
                const int rw = chunk >> 2, kc = chunk & 3;
                const int kcs = kc ^ (rw & 3);
                gld_lds16(A + (size_t)(row0 + rw) * Kfull + k0base + t * 32 + kcs * 8,
                          lA[buf] + cb * 8);
            }
        };
        auto stageB = [&](int t, int buf) {
#pragma unroll
            for (int r = 0; r < 2; ++r) {
                const int cb    = r * 256 + wave * 64;
                const int chunk = cb + lane;
                const int rw = chunk >> 2, kc = chunk & 3;
                const int kcs = kc ^ (rw & 3);
                gld_lds16(Bt + (size_t)(col0 + rw) * Kfull + k0base + t * 32 + kcs * 8,
                          (bf16*)lB[buf] + cb * 8);
            }
        };
        auto compute = [&](int buf) {
            bf16x8 af[4], bfr[4];
#pragma unroll
            for (int i = 0; i < 4; i++) {
                const int rowA = wm * 64 + i * 16 + lo;
                const int ca = hi ^ (lo & 3);
                af[i] = *(const bf16x8*)(lA[buf] + rowA * 32 + ca * 8);
            }
#pragma unroll
            for (int i = 0; i < 4; i++) {
                const int rowB = wn * 64 + i * 16 + lo;
                const int cc = hi ^ (lo & 3);
                bfr[i] = *(const bf16x8*)((const bf16*)lB[buf] + rowB * 32 + cc * 8);
            }
#pragma unroll
            for (int mi = 0; mi < 4; mi++)
#pragma unroll
                for (int ni = 0; ni < 4; ni++)
                    acc[mi][ni] = __builtin_amdgcn_mfma_f32_16x16x32_bf16(
                        af[mi], bfr[ni], acc[mi][ni], 0, 0, 0);
        };

        // prologue: tiles 0,1 in flight
        stageA(0, 0); stageB(0, 0);
        stageA(1, 1); stageB(1, 1);
        int cur = 0;
#pragma unroll 1
        for (int t = 0; t < nt; ++t) {
            if (t + 2 < nt) {
                const int nx = (cur >= 1) ? cur - 1 : 2;   // (cur+2)%3
                stageA(t + 2, nx); stageB(t + 2, nx);
                WAITV(8);        // own tile-t loads done; t+1,t+2 in flight
            } else if (t + 1 < nt) {
                WAITV(4);        // tile-t done; t+1 in flight
            } else {
                WAITV(0);        // last tile
            }
            __builtin_amdgcn_s_barrier();          // all waves: tile t ready
            __builtin_amdgcn_sched_barrier(0);
            compute(cur);
            WAITL0();                              // seal ds_reads of buf cur
            __builtin_amdgcn_sched_barrier(0);
            __builtin_amdgcn_s_barrier();          // buf cur reusable
            cur = (cur == 2) ? 0 : cur + 1;
        }
    } else {
        // ---- fp32 fallback: single-buffer BK=64, full-drain barriers ----
        for (int t = 0; t < nt; ++t) {
#pragma unroll
            for (int r = 0; r < 4; ++r) {
                const int cb    = r * 256 + wave * 64;
                const int chunk = cb + lane;
                const int rw = chunk >> 3, kc = chunk & 7;
                const int kcs = kc ^ (rw & 7);
                gld_lds16(A + (size_t)(row0 + rw) * Kfull + k0base + t * 64 + kcs * 8,
                          lA[0] + cb * 8);
            }
#pragma unroll
            for (int r = 0; r < 8; ++r) {
                const int cb    = r * 256 + wave * 64;
                const int chunk = cb + lane;
                const int rw = chunk >> 4, kc = chunk & 15;
                const int kcs = kc ^ ((rw & 7) << 1);
                gld_lds16(Bt + (size_t)(col0 + rw) * Kfull + k0base + t * 64 + kcs * 4,
                          (float*)lB[0] + cb * 4);
            }
            __syncthreads();
#pragma unroll 1
            for (int s = 0; s < 2; ++s) {
                bf16x8 af[4], bfr[4];
#pragma unroll
                for (int i = 0; i < 4; i++) {
                    const int rowA = wm * 64 + i * 16 + lo;
                    const int ca = (s * 4 + hi) ^ (lo & 7);
                    af[i] = *(const bf16x8*)(lA[0] + rowA * 64 + ca * 8);
                }
#pragma unroll
                for (int i = 0; i < 4; i++) {
                    const int rowB = wn * 64 + i * 16 + lo;
                    const float* base = (const float*)lB[0] + rowB * 64;
                    const int c0 = (s * 8 + hi * 2) ^ ((lo & 7) << 1);
                    const f32x4 u0 = *(const f32x4*)(base + c0 * 4);
                    const f32x4 u1 = *(const f32x4*)(base + (c0 + 1) * 4);
                    bf16x8 f;
#pragma unroll
                    for (int e = 0; e < 4; e++) { f[e] = (bf16)u0[e]; f[4+e] = (bf16)u1[e]; }
                    bfr[i] = f;
                }
#pragma unroll
                for (int mi = 0; mi < 4; mi++)
#pragma unroll
                    for (int ni = 0; ni < 4; ni++)
                        acc[mi][ni] = __builtin_amdgcn_mfma_f32_16x16x32_bf16(
                            af[mi], bfr[ni], acc[mi][ni], 0, 0, 0);
            }
            __syncthreads();
        }
    }

    // epilogue: C/D layout col=lane&15, row=(lane>>4)*4+reg
    const float bscale = (bz == 0) ? 1.0f : 0.0f;
#pragma unroll
    for (int mi = 0; mi < 4; mi++) {
#pragma unroll
        for (int ni = 0; ni < 4; ni++) {
            const int gcol = col0 + wn * 64 + ni * 16 + lo;
            const float bv = bias[gcol] * bscale;
#pragma unroll
            for (int r = 0; r < 4; r++) {
                const int grow = row0 + wm * 64 + mi * 16 + hi * 4 + r;
                float v = acc[mi][ni][r] + bv;
                if (MODE == 1) v = gelu_f(v);
                if (MODE == 2) {
                    atomicAdd(&resid[(size_t)grow * N + gcol], v);
                } else {
                    out[(size_t)grow * N + gcol] = (bf16)v;
                }
            }
        }
    }
}

// =====================================================================
// fp32 -> bf16 bulk convert (weights), 8 elems/lane
// =====================================================================
__global__ __launch_bounds__(256) void cvt_k(
    const float* __restrict__ src, bf16* __restrict__ dst)
{
    const int i = (blockIdx.x * 256 + threadIdx.x) * 8;
    const f32x4 a = *(const f32x4*)(src + i);
    const f32x4 b = *(const f32x4*)(src + i + 4);
    bf16x8 o;
#pragma unroll
    for (int e = 0; e < 4; e++) { o[e] = (bf16)a[e]; o[4 + e] = (bf16)b[e]; }
    *(bf16x8*)(dst + i) = o;
}

// =====================================================================
// LayerNorm: fp32 in [T,768] -> OutT out [T,768]; one wave per token
// =====================================================================
template<typename OutT>
__global__ __launch_bounds__(256) void ln_k(
    const float* __restrict__ x, const float* __restrict__ g,
    const float* __restrict__ b, OutT* __restrict__ out)
{
    const int wave = threadIdx.x >> 6, lane = threadIdx.x & 63;
    const int t = blockIdx.x * 4 + wave;
    const float* row = x + (size_t)t * C_;
    f32x4 v[3];
    float s = 0.f, ss = 0.f;
#pragma unroll
    for (int j = 0; j < 3; j++) {
        v[j] = *(const f32x4*)(row + (j * 64 + lane) * 4);
#pragma unroll
        for (int e = 0; e < 4; e++) { s += v[j][e]; ss += v[j][e] * v[j][e]; }
    }
#pragma unroll
    for (int off = 32; off > 0; off >>= 1) {
        s  += __shfl_xor(s, off);
        ss += __shfl_xor(ss, off);
    }
    const float mu  = s * (1.f / 768.f);
    const float var = ss * (1.f / 768.f) - mu * mu;
    const float rs  = rsqrtf(var + 1e-5f);
    OutT* orow = out + (size_t)t * C_;
#pragma unroll
    for (int j = 0; j < 3; j++) {
        const f32x4 gv = *(const f32x4*)(g + (j * 64 + lane) * 4);
        const f32x4 bv = *(const f32x4*)(b + (j * 64 + lane) * 4);
#pragma unroll
        for (int e = 0; e < 4; e++)
            orow[(j * 64 + lane) * 4 + e] = (OutT)((v[j][e] - mu) * rs * gv[e] + bv[e]);
    }
}

// =====================================================================
// x + pos_x (fp32) -> fp32 residual stream
// =====================================================================
__global__ __launch_bounds__(256) void addpos_k(
    const float* __restrict__ x, const float* __restrict__ p, float* __restrict__ o)
{
    const int i = (blockIdx.x * 256 + threadIdx.x) * 4;
    const f32x4 xv = *(const f32x4*)(x + i);
    const f32x4 pv = *(const f32x4*)(p + i);
    f32x4 ov;
#pragma unroll
    for (int e = 0; e < 4; e++) ov[e] = xv[e] + pv[e];
    *(f32x4*)(o + i) = ov;
}

// =====================================================================
// Flash attention: qkv bf16 [4096, 2304] -> out bf16 [4096, 768]
// 1-D grid (768) + XCD swizzle; KVBLK=128; T13 defer-max. (unchanged)
// =====================================================================
#define SKD_ 72     // lK row stride  [key][d]
#define SVK_ 136    // lV row stride  [d][key]  (128+8)
#define SPK_ 136    // lP row stride  [q][key]
__global__ __launch_bounds__(256) void attn_k(
    const bf16* __restrict__ qkv, bf16* __restrict__ out)
{
    const int id2 = (blockIdx.x & 7) * 96 + (blockIdx.x >> 3);  // 768 blocks
    const int qt = id2 & 15;            // 0..15
    const int bh = id2 >> 4;            // 0..47
    const int b = bh / H_, h = bh % H_;
    const int lane = threadIdx.x & 63, wave = threadIdx.x >> 6;
    const int lo = lane & 15, hi = lane >> 4;

    __shared__ __align__(16) bf16 lK[128 * SKD_];     // 18432 B [key][d]
    __shared__ __align__(16) bf16 lV[64 * SVK_];      // 17408 B V^T [d][key]
    __shared__ __align__(16) bf16 lP[4][16 * SPK_];   // 17408 B per-wave P

    const size_t tokbase = (size_t)b * N_;

    // persistent Q A-fragments, pre-scaled by 1/sqrt(HD)=0.125 (exact pow2)
    const bf16* qptr = qkv + (tokbase + qt * 64 + wave * 16 + lo) * (3 * C_) + h * HD_;
    bf16x8 qf0 = *(const bf16x8*)(qptr + hi * 8);
    bf16x8 qf1 = *(const bf16x8*)(qptr + 32 + hi * 8);
#pragma unroll
    for (int e = 0; e < 8; e++) {
        qf0[e] = (bf16)((float)qf0[e] * 0.125f);
        qf1[e] = (bf16)((float)qf1[e] * 0.125f);
    }

    float m_r[4], l_r[4];
    f32x4 oacc[4];
#pragma unroll
    for (int r = 0; r < 4; r++) { m_r[r] = -1e30f; l_r[r] = 0.f; }
#pragma unroll
    for (int di = 0; di < 4; di++) oacc[di] = (f32x4){0.f, 0.f, 0.f, 0.f};

    for (int kt = 0; kt < 8; ++kt) {
        const int kb0 = kt * 128;
        // ---- K: vectorized [key][d] staging (128 keys x 8 chunks) ----
#pragma unroll
        for (int r = 0; r < 4; ++r) {
            const int chunk = r * 256 + threadIdx.x;     // 0..1023
            const int key = chunk >> 3, dc = chunk & 7;
            const bf16* kp = qkv + (tokbase + kb0 + key) * (3 * C_) + C_ + h * HD_ + dc * 8;
            *(bf16x8*)(lK + key * SKD_ + dc * 8) = *(const bf16x8*)kp;
        }
        // ---- V^T: transposed coalesced loads (lane d, 8 keys/chunk) ----
#pragma unroll
        for (int r = 0; r < 4; ++r) {
            const int chunk = r * 256 + threadIdx.x;     // 0..1023
            const int d = chunk & 63, kg = chunk >> 6;   // kg 0..15
            const bf16* vp = qkv + (tokbase + kb0 + kg * 8) * (3 * C_)
                           + 2 * C_ + h * HD_ + d;
            bf16x8 tv;
#pragma unroll
            for (int i = 0; i < 8; i++) tv[i] = vp[(size_t)i * (3 * C_)];
            *(bf16x8*)(lV + d * SVK_ + kg * 8) = tv;
        }
        __syncthreads();

        // ---- S = Q @ K^T (per wave: 16 q x 128 keys), already scaled ----
        f32x4 sacc[8];
#pragma unroll
        for (int kb = 0; kb < 8; kb++) {
            const bf16x8 b0 = *(const bf16x8*)(lK + (kb * 16 + lo) * SKD_ + hi * 8);
            const bf16x8 b1 = *(const bf16x8*)(lK + (kb * 16 + lo) * SKD_ + 32 + hi * 8);
            f32x4 a = (f32x4){0.f, 0.f, 0.f, 0.f};
            a = __builtin_amdgcn_mfma_f32_16x16x32_bf16(qf0, b0, a, 0, 0, 0);
            a = __builtin_amdgcn_mfma_f32_16x16x32_bf16(qf1, b1, a, 0, 0, 0);
            sacc[kb] = a;
        }

        // ---- online softmax, defer-max (row r = q row hi*4+r) ----
        float pm[4], mn[4], ts[4];
#pragma unroll
        for (int r = 0; r < 4; r++) {
            float a0 = fmaxf(fmaxf(sacc[0][r], sacc[1][r]),
                             fmaxf(sacc[2][r], sacc[3][r]));
            float a1 = fmaxf(fmaxf(sacc[4][r], sacc[5][r]),
                             fmaxf(sacc[6][r], sacc[7][r]));
            pm[r] = fmaxf(a0, a1);
            ts[r] = 0.f;
        }
        const int okd = (pm[0] <= m_r[0] + 8.f) && (pm[1] <= m_r[1] + 8.f)
                     && (pm[2] <= m_r[2] + 8.f) && (pm[3] <= m_r[3] + 8.f);
        const bool defer = __all(okd);
        if (defer) {
#pragma unroll
            for (int r = 0; r < 4; r++) mn[r] = m_r[r];
        } else {
#pragma unroll
            for (int r = 0; r < 4; r++) {
                float tm = pm[r];
#pragma unroll
                for (int off = 1; off < 16; off <<= 1)
                    tm = fmaxf(tm, __shfl_xor(tm, off));
                mn[r] = fmaxf(m_r[r], tm);
            }
        }
        // stream: exp -> wave-private lP -> partial sum
#pragma unroll
        for (int kb = 0; kb < 8; kb++)
#pragma unroll
            for (int r = 0; r < 4; r++) {
                const float p = __expf(sacc[kb][r] - mn[r]);
                lP[wave][(hi * 4 + r) * SPK_ + kb * 16 + lo] = (bf16)p;
                ts[r] += p;
            }
#pragma unroll
        for (int r = 0; r < 4; r++)
#pragma unroll
            for (int off = 1; off < 16; off <<= 1)
                ts[r] += __shfl_xor(ts[r], off);
        if (defer) {
#pragma unroll
            for (int r = 0; r < 4; r++) l_r[r] += ts[r];
        } else {
            float alpha[4];
#pragma unroll
            for (int r = 0; r < 4; r++) {
                alpha[r] = __expf(m_r[r] - mn[r]);
                l_r[r] = l_r[r] * alpha[r] + ts[r];
                m_r[r] = mn[r];
            }
#pragma unroll
            for (int di = 0; di < 4; di++)
#pragma unroll
                for (int r = 0; r < 4; r++) oacc[di][r] *= alpha[r];
        }

        // ---- PV: P A-frags (wave-private, no barrier needed) ----
        bf16x8 pa[4];
#pragma unroll
        for (int s = 0; s < 4; s++)
            pa[s] = *(const bf16x8*)(&lP[wave][lo * SPK_ + s * 32 + hi * 8]);
#pragma unroll
        for (int di = 0; di < 4; di++) {
#pragma unroll
            for (int s = 0; s < 4; s++) {
                const bf16x8 v = *(const bf16x8*)(lV + (di * 16 + lo) * SVK_ + s * 32 + hi * 8);
                oacc[di] = __builtin_amdgcn_mfma_f32_16x16x32_bf16(pa[s], v, oacc[di], 0, 0, 0);
            }
        }
        __syncthreads();
    }

    // ---- epilogue: O * (1/l) ----
    float il[4];
#pragma unroll
    for (int r = 0; r < 4; r++) il[r] = 1.0f / l_r[r];
#pragma unroll
    for (int di = 0; di < 4; di++)
#pragma unroll
        for (int r = 0; r < 4; r++) {
            const size_t tok = tokbase + qt * 64 + wave * 16 + hi * 4 + r;
            out[tok * C_ + h * HD_ + di * 16 + lo] = (bf16)(oacc[di][r] * il[r]);
        }
}

// =====================================================================
extern "C" void kernel_launch(void* const* d_in, const int* in_sizes, int n_in,
                              void* d_out, int out_size, void* d_ws, size_t ws_size,
                              hipStream_t stream)
{
    const float* x      = (const float*)d_in[0];
    const float* pos_x  = (const float*)d_in[1];
    const float* qkv_w  = (const float*)d_in[2];
    const float* qkv_b  = (const float*)d_in[3];
    const float* proj_w = (const float*)d_in[4];
    const float* proj_b = (const float*)d_in[5];
    const float* fc1_w  = (const float*)d_in[6];
    const float* fc1_b  = (const float*)d_in[7];
    const float* fc2_w  = (const float*)d_in[8];
    const float* fc2_b  = (const float*)d_in[9];
    const float* ln1_g  = (const float*)d_in[10];
    const float* ln1_b  = (const float*)d_in[11];
    const float* ln2_g  = (const float*)d_in[12];
    const float* ln2_b  = (const float*)d_in[13];
    const float* nf_g   = (const float*)d_in[14];
    const float* nf_b   = (const float*)d_in[15];

    char* ws = (char*)d_ws;
    float* xres  = (float*)(ws);                         // 12,582,912 B
    bf16* hbuf   = (bf16*)(ws + 12582912);               //  6,291,456
    bf16* qkvbuf = (bf16*)(ws + 18874368);               // 18,874,368
    bf16* attno  = (bf16*)(ws + 37748736);               //  6,291,456
    bf16* hid    = (bf16*)(ws + 44040192);               // 25,165,824 (end 69,206,016)
    bf16* wq     = (bf16*)(ws + 69206016);               // 42,467,328
    bf16* wp     = (bf16*)(ws + 111673344);              // 14,155,776
    bf16* w1     = (bf16*)(ws + 125829120);              // 56,623,104
    bf16* w2     = (bf16*)(ws + 182452224);              // 56,623,104 (end 239,075,328)
    const bool usebf16 = ws_size >= (size_t)239075328;

    addpos_k<<<T_ * C_ / 4 / 256, 256, 0, stream>>>(x, pos_x, xres);

    if (usebf16) {
        cvt_k<<<D_ * 3 * C_ * C_ / 2048, 256, 0, stream>>>(qkv_w, wq);
        cvt_k<<<D_ * C_ * C_ / 2048, 256, 0, stream>>>(proj_w, wp);
        cvt_k<<<D_ * FF_ * C_ / 2048, 256, 0, stream>>>(fc1_w, w1);
        cvt_k<<<D_ * C_ * FF_ / 2048, 256, 0, stream>>>(fc2_w, w2);
    }

    // 1-D grids (XCD swizzle decode inside kernels)
    const int g_qkv  = (T_/128) * ((3*C_)/128);      // 576
    const int g_proj = (T_/128) * (C_/128) * 2;      // 384
    const int g_fc1  = (T_/128) * (FF_/128);         // 768
    const int g_fc2  = (T_/128) * (C_/128) * 2;      // 384

    for (int L = 0; L < D_; ++L) {
        ln_k<bf16><<<T_ / 4, 256, 0, stream>>>(xres, ln1_g + L * C_, ln1_b + L * C_, hbuf);
        if (usebf16) {
            gemm_bt<bf16,0><<<g_qkv, 256, 0, stream>>>(
                hbuf, wq + (size_t)L * 3 * C_ * C_, qkv_b + (size_t)L * 3 * C_,
                qkvbuf, nullptr, T_, 3 * C_, C_, C_);
        } else {
            gemm_bt<float,0><<<g_qkv, 256, 0, stream>>>(
                hbuf, qkv_w + (size_t)L * 3 * C_ * C_, qkv_b + (size_t)L * 3 * C_,
                qkvbuf, nullptr, T_, 3 * C_, C_, C_);
        }
        attn_k<<<N_ / 64 * B_ * H_, 256, 0, stream>>>(qkvbuf, attno);
        if (usebf16) {
            gemm_bt<bf16,2><<<g_proj, 256, 0, stream>>>(
                attno, wp + (size_t)L * C_ * C_, proj_b + (size_t)L * C_,
                nullptr, xres, T_, C_, C_, C_ / 2);
        } else {
            gemm_bt<float,2><<<g_proj, 256, 0, stream>>>(
                attno, proj_w + (size_t)L * C_ * C_, proj_b + (size_t)L * C_,
                nullptr, xres, T_, C_, C_, C_ / 2);
        }
        ln_k<bf16><<<T_ / 4, 256, 0, stream>>>(xres, ln2_g + L * C_, ln2_b + L * C_, hbuf);
        if (usebf16) {
            gemm_bt<bf16,1><<<g_fc1, 256, 0, stream>>>(
                hbuf, w1 + (size_t)L * FF_ * C_, fc1_b + (size_t)L * FF_,
                hid, nullptr, T_, FF_, C_, C_);
            gemm_bt<bf16,2><<<g_fc2, 256, 0, stream>>>(
                hid, w2 + (size_t)L * C_ * FF_, fc2_b + (size_t)L * C_,
                nullptr, xres, T_, C_, FF_, FF_ / 2);
        } else {
            gemm_bt<float,1><<<g_fc1, 256, 0, stream>>>(
                hbuf, fc1_w + (size_t)L * FF_ * C_, fc1_b + (size_t)L * FF_,
                hid, nullptr, T_, FF_, C_, C_);
            gemm_bt<float,2><<<g_fc2, 256, 0, stream>>>(
                hid, fc2_w + (size_t)L * C_ * FF_, fc2_b + (size_t)L * C_,
                nullptr, xres, T_, C_, FF_, FF_ / 2);
        }
    }
    ln_k<float><<<T_ / 4, 256, 0, stream>>>(xres, nf_g, nf_b, (float*)d_out);
}

// Round 6
// 2590.881 us; speedup vs baseline: 1.1289x; 1.1289x over previous
//
#include <hip/hip_runtime.h>
#include <hip/hip_bf16.h>
#include <math.h>

typedef __bf16 bf16;
typedef __bf16 bf16x8 __attribute__((ext_vector_type(8)));
typedef __bf16 bf16x4 __attribute__((ext_vector_type(4)));
typedef float  f32x4  __attribute__((ext_vector_type(4)));

#define B_  4
#define N_  1024
#define C_  768
#define H_  12
#define HD_ 64
#define FF_ 3072
#define T_  (B_*N_)      // 4096 tokens
#define D_  12

// ---- async global->LDS, 16B per lane, wave-uniform LDS base ----
__device__ __forceinline__ void gld_lds16(const void* g, void* l) {
    __builtin_amdgcn_global_load_lds(
        (const __attribute__((address_space(1))) void*)g,
        (__attribute__((address_space(3))) void*)l, 16, 0, 0);
}

// ---- exact-enough GELU: A&S 7.1.26 erf, |err|<=1.5e-7 (invisible in bf16)
__device__ __forceinline__ float gelu_f(float v) {
    const float ax = fabsf(v) * 0.70710678118f;
    const float t  = __frcp_rn(1.0f + 0.3275911f * ax);
    float p = 1.061405429f;
    p = p * t - 1.453152027f;
    p = p * t + 1.421413741f;
    p = p * t - 0.284496736f;
    p = p * t + 0.254829592f;
    const float e = p * t * __expf(-ax * ax);
    const float erfv = (v >= 0.f) ? (1.0f - e) : (e - 1.0f);
    return 0.5f * v * (1.0f + erfv);
}

// =====================================================================
// GEMM:  out[M,N] = A[M,K] @ Bt[N,K]^T + bias
// MODE 0: store bf16   MODE 1: GELU then store bf16
// MODE 2: resid[M,N] (fp32) atomicAdd (split-K safe; bias only on z==0)
// 64x128 tile (was 128x128): round-3 counters showed Occupancy 30% with
// grid=3 blocks/CU (768 blocks) while resources allowed 5 -- the kernel
// was GRID-STARVED, so latency had no TLP to hide under (two intra-wave
// pipeline attempts both regressed; wave-overlap is the HW-native fix).
// 64x128 doubles every grid: fc1 1536 (6/CU), qkv 1152, proj/fc2 768.
// LDS 24 KB, 4 waves 2x2, wave = 32x64 = acc[2][4], BK=64, two K=32
// sub-steps; simple 2-barrier loop (round-3 structure, proven).
// LDS XOR-swizzle both-sides; 1-D grid + XCD swizzle (T1).
// =====================================================================
template<typename WT, int MODE>
__global__ __launch_bounds__(256) void gemm_bt(
    const bf16* __restrict__ A, const WT* __restrict__ Bt,
    const float* __restrict__ bias, bf16* __restrict__ out,
    float* __restrict__ resid, int M, int N, int Kfull, int Ks)
{
    __shared__ __align__(16) bf16 lA[64*64];    // 8 KB   [row][64k] swizzled
    __shared__ __align__(16) WT   lB[128*64];   // 16 KB bf16 / 32 KB f32
    const int tid  = threadIdx.x;
    const int lane = tid & 63, wave = tid >> 6;
    const int lo = lane & 15, hi = lane >> 4;
    const int wm = wave & 1, wn = wave >> 1;

    // XCD swizzle: nblk % 8 == 0 for all call sites -> bijective
    const int nblk = gridDim.x;
    const int id2  = (blockIdx.x & 7) * (nblk >> 3) + (blockIdx.x >> 3);
    const int gx = M >> 6, gy = N >> 7;
    const int bx  = id2 % gx;
    const int byz = id2 / gx;
    const int by  = byz % gy;
    const int bz  = byz / gy;
    const int row0 = bx * 64, col0 = by * 128;
    const int k0base = bz * Ks;

    f32x4 acc[2][4];
#pragma unroll
    for (int i = 0; i < 2; i++)
#pragma unroll
        for (int j = 0; j < 4; j++) acc[i][j] = (f32x4){0.f, 0.f, 0.f, 0.f};

    for (int k0 = k0base; k0 < k0base + Ks; k0 += 64) {
        // A tile 64x64: 512 chunks x 16B, LDS linear [row][8 chunks],
        // global source chunk = kc ^ (row&7)
#pragma unroll
        for (int r = 0; r < 2; ++r) {
            const int cb    = r * 256 + wave * 64;   // wave-uniform base
            const int chunk = cb + lane;
            const int rw = chunk >> 3, kc = chunk & 7;
            const int kcs = kc ^ (rw & 7);
            gld_lds16(A + (size_t)(row0 + rw) * Kfull + k0 + kcs * 8, lA + cb * 8);
        }
        if constexpr (sizeof(WT) == 2) {
            // B tile 128x64 bf16: 1024 chunks
#pragma unroll
            for (int r = 0; r < 4; ++r) {
                const int cb    = r * 256 + wave * 64;
                const int chunk = cb + lane;
                const int rw = chunk >> 3, kc = chunk & 7;
                const int kcs = kc ^ (rw & 7);
                gld_lds16(Bt + (size_t)(col0 + rw) * Kfull + k0 + kcs * 8,
                          (bf16*)lB + cb * 8);
            }
        } else {
            // B tile fp32: 2048 chunks x 16B, swizzle kc ^ ((row&7)<<1)
#pragma unroll
            for (int r = 0; r < 8; ++r) {
                const int cb    = r * 256 + wave * 64;
                const int chunk = cb + lane;
                const int rw = chunk >> 4, kc = chunk & 15;
                const int kcs = kc ^ ((rw & 7) << 1);
                gld_lds16(Bt + (size_t)(col0 + rw) * Kfull + k0 + kcs * 4,
                          (float*)lB + cb * 4);
            }
        }
        __syncthreads();
        // two K=32 sub-steps; NOT unrolled (register liveness)
#pragma unroll 1
        for (int s = 0; s < 2; ++s) {
            bf16x8 af[2], bfr[4];
#pragma unroll
            for (int i = 0; i < 2; i++) {
                const int rowA = wm * 32 + i * 16 + lo;
                const int ca = (s * 4 + hi) ^ (lo & 7);
                af[i] = *(const bf16x8*)(lA + rowA * 64 + ca * 8);
            }
#pragma unroll
            for (int i = 0; i < 4; i++) {
                const int rowB = wn * 64 + i * 16 + lo;
                if constexpr (sizeof(WT) == 2) {
                    const int cc = (s * 4 + hi) ^ (lo & 7);
                    bfr[i] = *(const bf16x8*)((const bf16*)lB + rowB * 64 + cc * 8);
                } else {
                    const float* base = (const float*)lB + rowB * 64;
                    const int c0 = (s * 8 + hi * 2) ^ ((lo & 7) << 1);
                    const f32x4 u0 = *(const f32x4*)(base + c0 * 4);
                    const f32x4 u1 = *(const f32x4*)(base + (c0 + 1) * 4);
                    bf16x8 f;
#pragma unroll
                    for (int e = 0; e < 4; e++) { f[e] = (bf16)u0[e]; f[4+e] = (bf16)u1[e]; }
                    bfr[i] = f;
                }
            }
#pragma unroll
            for (int mi = 0; mi < 2; mi++)
#pragma unroll
                for (int ni = 0; ni < 4; ni++)
                    acc[mi][ni] = __builtin_amdgcn_mfma_f32_16x16x32_bf16(
                        af[mi], bfr[ni], acc[mi][ni], 0, 0, 0);
        }
        __syncthreads();
    }

    // epilogue: C/D layout col=lane&15, row=(lane>>4)*4+reg
    const float bscale = (bz == 0) ? 1.0f : 0.0f;
#pragma unroll
    for (int mi = 0; mi < 2; mi++) {
#pragma unroll
        for (int ni = 0; ni < 4; ni++) {
            const int gcol = col0 + wn * 64 + ni * 16 + lo;
            const float bv = bias[gcol] * bscale;
#pragma unroll
            for (int r = 0; r < 4; r++) {
                const int grow = row0 + wm * 32 + mi * 16 + hi * 4 + r;
                float v = acc[mi][ni][r] + bv;
                if (MODE == 1) v = gelu_f(v);
                if (MODE == 2) {
                    atomicAdd(&resid[(size_t)grow * N + gcol], v);
                } else {
                    out[(size_t)grow * N + gcol] = (bf16)v;
                }
            }
        }
    }
}

// =====================================================================
// fp32 -> bf16 bulk convert (weights), 8 elems/lane
// =====================================================================
__global__ __launch_bounds__(256) void cvt_k(
    const float* __restrict__ src, bf16* __restrict__ dst)
{
    const int i = (blockIdx.x * 256 + threadIdx.x) * 8;
    const f32x4 a = *(const f32x4*)(src + i);
    const f32x4 b = *(const f32x4*)(src + i + 4);
    bf16x8 o;
#pragma unroll
    for (int e = 0; e < 4; e++) { o[e] = (bf16)a[e]; o[4 + e] = (bf16)b[e]; }
    *(bf16x8*)(dst + i) = o;
}

// =====================================================================
// LayerNorm: fp32 in [T,768] -> OutT out [T,768]; one wave per token
// =====================================================================
template<typename OutT>
__global__ __launch_bounds__(256) void ln_k(
    const float* __restrict__ x, const float* __restrict__ g,
    const float* __restrict__ b, OutT* __restrict__ out)
{
    const int wave = threadIdx.x >> 6, lane = threadIdx.x & 63;
    const int t = blockIdx.x * 4 + wave;
    const float* row = x + (size_t)t * C_;
    f32x4 v[3];
    float s = 0.f, ss = 0.f;
#pragma unroll
    for (int j = 0; j < 3; j++) {
        v[j] = *(const f32x4*)(row + (j * 64 + lane) * 4);
#pragma unroll
        for (int e = 0; e < 4; e++) { s += v[j][e]; ss += v[j][e] * v[j][e]; }
    }
#pragma unroll
    for (int off = 32; off > 0; off >>= 1) {
        s  += __shfl_xor(s, off);
        ss += __shfl_xor(ss, off);
    }
    const float mu  = s * (1.f / 768.f);
    const float var = ss * (1.f / 768.f) - mu * mu;
    const float rs  = rsqrtf(var + 1e-5f);
    OutT* orow = out + (size_t)t * C_;
#pragma unroll
    for (int j = 0; j < 3; j++) {
        const f32x4 gv = *(const f32x4*)(g + (j * 64 + lane) * 4);
        const f32x4 bv = *(const f32x4*)(b + (j * 64 + lane) * 4);
#pragma unroll
        for (int e = 0; e < 4; e++)
            orow[(j * 64 + lane) * 4 + e] = (OutT)((v[j][e] - mu) * rs * gv[e] + bv[e]);
    }
}

// =====================================================================
// x + pos_x (fp32) -> fp32 residual stream
// =====================================================================
__global__ __launch_bounds__(256) void addpos_k(
    const float* __restrict__ x, const float* __restrict__ p, float* __restrict__ o)
{
    const int i = (blockIdx.x * 256 + threadIdx.x) * 4;
    const f32x4 xv = *(const f32x4*)(x + i);
    const f32x4 pv = *(const f32x4*)(p + i);
    f32x4 ov;
#pragma unroll
    for (int e = 0; e < 4; e++) ov[e] = xv[e] + pv[e];
    *(f32x4*)(o + i) = ov;
}

// =====================================================================
// Flash attention: qkv bf16 [4096, 2304] -> out bf16 [4096, 768]
// 1-D grid (768) + XCD swizzle; KVBLK=128; T13 defer-max. (round-3 ver)
// =====================================================================
#define SKD_ 72     // lK row stride  [key][d]
#define SVK_ 136    // lV row stride  [d][key]  (128+8)
#define SPK_ 136    // lP row stride  [q][key]
__global__ __launch_bounds__(256) void attn_k(
    const bf16* __restrict__ qkv, bf16* __restrict__ out)
{
    const int id2 = (blockIdx.x & 7) * 96 + (blockIdx.x >> 3);  // 768 blocks
    const int qt = id2 & 15;            // 0..15
    const int bh = id2 >> 4;            // 0..47
    const int b = bh / H_, h = bh % H_;
    const int lane = threadIdx.x & 63, wave = threadIdx.x >> 6;
    const int lo = lane & 15, hi = lane >> 4;

    __shared__ __align__(16) bf16 lK[128 * SKD_];     // 18432 B [key][d]
    __shared__ __align__(16) bf16 lV[64 * SVK_];      // 17408 B V^T [d][key]
    __shared__ __align__(16) bf16 lP[4][16 * SPK_];   // 17408 B per-wave P

    const size_t tokbase = (size_t)b * N_;

    // persistent Q A-fragments, pre-scaled by 1/sqrt(HD)=0.125 (exact pow2)
    const bf16* qptr = qkv + (tokbase + qt * 64 + wave * 16 + lo) * (3 * C_) + h * HD_;
    bf16x8 qf0 = *(const bf16x8*)(qptr + hi * 8);
    bf16x8 qf1 = *(const bf16x8*)(qptr + 32 + hi * 8);
#pragma unroll
    for (int e = 0; e < 8; e++) {
        qf0[e] = (bf16)((float)qf0[e] * 0.125f);
        qf1[e] = (bf16)((float)qf1[e] * 0.125f);
    }

    float m_r[4], l_r[4];
    f32x4 oacc[4];
#pragma unroll
    for (int r = 0; r < 4; r++) { m_r[r] = -1e30f; l_r[r] = 0.f; }
#pragma unroll
    for (int di = 0; di < 4; di++) oacc[di] = (f32x4){0.f, 0.f, 0.f, 0.f};

    for (int kt = 0; kt < 8; ++kt) {
        const int kb0 = kt * 128;
        // ---- K: vectorized [key][d] staging (128 keys x 8 chunks) ----
#pragma unroll
        for (int r = 0; r < 4; ++r) {
            const int chunk = r * 256 + threadIdx.x;     // 0..1023
            const int key = chunk >> 3, dc = chunk & 7;
            const bf16* kp = qkv + (tokbase + kb0 + key) * (3 * C_) + C_ + h * HD_ + dc * 8;
            *(bf16x8*)(lK + key * SKD_ + dc * 8) = *(const bf16x8*)kp;
        }
        // ---- V^T: transposed coalesced loads (lane d, 8 keys/chunk) ----
#pragma unroll
        for (int r = 0; r < 4; ++r) {
            const int chunk = r * 256 + threadIdx.x;     // 0..1023
            const int d = chunk & 63, kg = chunk >> 6;   // kg 0..15
            const bf16* vp = qkv + (tokbase + kb0 + kg * 8) * (3 * C_)
                           + 2 * C_ + h * HD_ + d;
            bf16x8 tv;
#pragma unroll
            for (int i = 0; i < 8; i++) tv[i] = vp[(size_t)i * (3 * C_)];
            *(bf16x8*)(lV + d * SVK_ + kg * 8) = tv;
        }
        __syncthreads();

        // ---- S = Q @ K^T (per wave: 16 q x 128 keys), already scaled ----
        f32x4 sacc[8];
#pragma unroll
        for (int kb = 0; kb < 8; kb++) {
            const bf16x8 b0 = *(const bf16x8*)(lK + (kb * 16 + lo) * SKD_ + hi * 8);
            const bf16x8 b1 = *(const bf16x8*)(lK + (kb * 16 + lo) * SKD_ + 32 + hi * 8);
            f32x4 a = (f32x4){0.f, 0.f, 0.f, 0.f};
            a = __builtin_amdgcn_mfma_f32_16x16x32_bf16(qf0, b0, a, 0, 0, 0);
            a = __builtin_amdgcn_mfma_f32_16x16x32_bf16(qf1, b1, a, 0, 0, 0);
            sacc[kb] = a;
        }

        // ---- online softmax, defer-max (row r = q row hi*4+r) ----
        float pm[4], mn[4], ts[4];
#pragma unroll
        for (int r = 0; r < 4; r++) {
            float a0 = fmaxf(fmaxf(sacc[0][r], sacc[1][r]),
                             fmaxf(sacc[2][r], sacc[3][r]));
            float a1 = fmaxf(fmaxf(sacc[4][r], sacc[5][r]),
                             fmaxf(sacc[6][r], sacc[7][r]));
            pm[r] = fmaxf(a0, a1);
            ts[r] = 0.f;
        }
        const int okd = (pm[0] <= m_r[0] + 8.f) && (pm[1] <= m_r[1] + 8.f)
                     && (pm[2] <= m_r[2] + 8.f) && (pm[3] <= m_r[3] + 8.f);
        const bool defer = __all(okd);
        if (defer) {
#pragma unroll
            for (int r = 0; r < 4; r++) mn[r] = m_r[r];
        } else {
#pragma unroll
            for (int r = 0; r < 4; r++) {
                float tm = pm[r];
#pragma unroll
                for (int off = 1; off < 16; off <<= 1)
                    tm = fmaxf(tm, __shfl_xor(tm, off));
                mn[r] = fmaxf(m_r[r], tm);
            }
        }
        // stream: exp -> wave-private lP -> partial sum
#pragma unroll
        for (int kb = 0; kb < 8; kb++)
#pragma unroll
            for (int r = 0; r < 4; r++) {
                const float p = __expf(sacc[kb][r] - mn[r]);
                lP[wave][(hi * 4 + r) * SPK_ + kb * 16 + lo] = (bf16)p;
                ts[r] += p;
            }
#pragma unroll
        for (int r = 0; r < 4; r++)
#pragma unroll
            for (int off = 1; off < 16; off <<= 1)
                ts[r] += __shfl_xor(ts[r], off);
        if (defer) {
#pragma unroll
            for (int r = 0; r < 4; r++) l_r[r] += ts[r];
        } else {
            float alpha[4];
#pragma unroll
            for (int r = 0; r < 4; r++) {
                alpha[r] = __expf(m_r[r] - mn[r]);
                l_r[r] = l_r[r] * alpha[r] + ts[r];
                m_r[r] = mn[r];
            }
#pragma unroll
            for (int di = 0; di < 4; di++)
#pragma unroll
                for (int r = 0; r < 4; r++) oacc[di][r] *= alpha[r];
        }

        // ---- PV: P A-frags (wave-private, no barrier needed) ----
        bf16x8 pa[4];
#pragma unroll
        for (int s = 0; s < 4; s++)
            pa[s] = *(const bf16x8*)(&lP[wave][lo * SPK_ + s * 32 + hi * 8]);
#pragma unroll
        for (int di = 0; di < 4; di++) {
#pragma unroll
            for (int s = 0; s < 4; s++) {
                const bf16x8 v = *(const bf16x8*)(lV + (di * 16 + lo) * SVK_ + s * 32 + hi * 8);
                oacc[di] = __builtin_amdgcn_mfma_f32_16x16x32_bf16(pa[s], v, oacc[di], 0, 0, 0);
            }
        }
        __syncthreads();
    }

    // ---- epilogue: O * (1/l) ----
    float il[4];
#pragma unroll
    for (int r = 0; r < 4; r++) il[r] = 1.0f / l_r[r];
#pragma unroll
    for (int di = 0; di < 4; di++)
#pragma unroll
        for (int r = 0; r < 4; r++) {
            const size_t tok = tokbase + qt * 64 + wave * 16 + hi * 4 + r;
            out[tok * C_ + h * HD_ + di * 16 + lo] = (bf16)(oacc[di][r] * il[r]);
        }
}

// =====================================================================
extern "C" void kernel_launch(void* const* d_in, const int* in_sizes, int n_in,
                              void* d_out, int out_size, void* d_ws, size_t ws_size,
                              hipStream_t stream)
{
    const float* x      = (const float*)d_in[0];
    const float* pos_x  = (const float*)d_in[1];
    const float* qkv_w  = (const float*)d_in[2];
    const float* qkv_b  = (const float*)d_in[3];
    const float* proj_w = (const float*)d_in[4];
    const float* proj_b = (const float*)d_in[5];
    const float* fc1_w  = (const float*)d_in[6];
    const float* fc1_b  = (const float*)d_in[7];
    const float* fc2_w  = (const float*)d_in[8];
    const float* fc2_b  = (const float*)d_in[9];
    const float* ln1_g  = (const float*)d_in[10];
    const float* ln1_b  = (const float*)d_in[11];
    const float* ln2_g  = (const float*)d_in[12];
    const float* ln2_b  = (const float*)d_in[13];
    const float* nf_g   = (const float*)d_in[14];
    const float* nf_b   = (const float*)d_in[15];

    char* ws = (char*)d_ws;
    float* xres  = (float*)(ws);                         // 12,582,912 B
    bf16* hbuf   = (bf16*)(ws + 12582912);               //  6,291,456
    bf16* qkvbuf = (bf16*)(ws + 18874368);               // 18,874,368
    bf16* attno  = (bf16*)(ws + 37748736);               //  6,291,456
    bf16* hid    = (bf16*)(ws + 44040192);               // 25,165,824 (end 69,206,016)
    bf16* wq     = (bf16*)(ws + 69206016);               // 42,467,328
    bf16* wp     = (bf16*)(ws + 111673344);              // 14,155,776
    bf16* w1     = (bf16*)(ws + 125829120);              // 56,623,104
    bf16* w2     = (bf16*)(ws + 182452224);              // 56,623,104 (end 239,075,328)
    const bool usebf16 = ws_size >= (size_t)239075328;

    addpos_k<<<T_ * C_ / 4 / 256, 256, 0, stream>>>(x, pos_x, xres);

    if (usebf16) {
        cvt_k<<<D_ * 3 * C_ * C_ / 2048, 256, 0, stream>>>(qkv_w, wq);
        cvt_k<<<D_ * C_ * C_ / 2048, 256, 0, stream>>>(proj_w, wp);
        cvt_k<<<D_ * FF_ * C_ / 2048, 256, 0, stream>>>(fc1_w, w1);
        cvt_k<<<D_ * C_ * FF_ / 2048, 256, 0, stream>>>(fc2_w, w2);
    }

    // 1-D grids, 64-row tiles (XCD swizzle decode inside kernels)
    const int g_qkv  = (T_/64) * ((3*C_)/128);       // 1152
    const int g_proj = (T_/64) * (C_/128) * 2;       // 768
    const int g_fc1  = (T_/64) * (FF_/128);          // 1536
    const int g_fc2  = (T_/64) * (C_/128) * 2;       // 768

    for (int L = 0; L < D_; ++L) {
        ln_k<bf16><<<T_ / 4, 256, 0, stream>>>(xres, ln1_g + L * C_, ln1_b + L * C_, hbuf);
        if (usebf16) {
            gemm_bt<bf16,0><<<g_qkv, 256, 0, stream>>>(
                hbuf, wq + (size_t)L * 3 * C_ * C_, qkv_b + (size_t)L * 3 * C_,
                qkvbuf, nullptr, T_, 3 * C_, C_, C_);
        } else {
            gemm_bt<float,0><<<g_qkv, 256, 0, stream>>>(
                hbuf, qkv_w + (size_t)L * 3 * C_ * C_, qkv_b + (size_t)L * 3 * C_,
                qkvbuf, nullptr, T_, 3 * C_, C_, C_);
        }
        attn_k<<<N_ / 64 * B_ * H_, 256, 0, stream>>>(qkvbuf, attno);
        if (usebf16) {
            gemm_bt<bf16,2><<<g_proj, 256, 0, stream>>>(
                attno, wp + (size_t)L * C_ * C_, proj_b + (size_t)L * C_,
                nullptr, xres, T_, C_, C_, C_ / 2);
        } else {
            gemm_bt<float,2><<<g_proj, 256, 0, stream>>>(
                attno, proj_w + (size_t)L * C_ * C_, proj_b + (size_t)L * C_,
                nullptr, xres, T_, C_, C_, C_ / 2);
        }
        ln_k<bf16><<<T_ / 4, 256, 0, stream>>>(xres, ln2_g + L * C_, ln2_b + L * C_, hbuf);
        if (usebf16) {
            gemm_bt<bf16,1><<<g_fc1, 256, 0, stream>>>(
                hbuf, w1 + (size_t)L * FF_ * C_, fc1_b + (size_t)L * FF_,
                hid, nullptr, T_, FF_, C_, C_);
            gemm_bt<bf16,2><<<g_fc2, 256, 0, stream>>>(
                hid, w2 + (size_t)L * C_ * FF_, fc2_b + (size_t)L * C_,
                nullptr, xres, T_, C_, FF_, FF_ / 2);
        } else {
            gemm_bt<float,1><<<g_fc1, 256, 0, stream>>>(
                hbuf, fc1_w + (size_t)L * FF_ * C_, fc1_b + (size_t)L * FF_,
                hid, nullptr, T_, FF_, C_, C_);
            gemm_bt<float,2><<<g_fc2, 256, 0, stream>>>(
                hid, fc2_w + (size_t)L * C_ * FF_, fc2_b + (size_t)L * C_,
                nullptr, xres, T_, C_, FF_, FF_ / 2);
        }
    }
    ln_k<float><<<T_ / 4, 256, 0, stream>>>(xres, nf_g, nf_b, (float*)d_out);
}

// Round 7
// 2511.900 us; speedup vs baseline: 1.1644x; 1.0314x over previous
//
#include <hip/hip_runtime.h>
#include <hip/hip_bf16.h>
#include <math.h>

typedef __bf16 bf16;
typedef __bf16 bf16x8 __attribute__((ext_vector_type(8)));
typedef __bf16 bf16x4 __attribute__((ext_vector_type(4)));
typedef float  f32x4  __attribute__((ext_vector_type(4)));

#define B_  4
#define N_  1024
#define C_  768
#define H_  12
#define HD_ 64
#define FF_ 3072
#define T_  (B_*N_)      // 4096 tokens
#define D_  12

// ---- async global->LDS, 16B per lane, wave-uniform LDS base ----
__device__ __forceinline__ void gld_lds16(const void* g, void* l) {
    __builtin_amdgcn_global_load_lds(
        (const __attribute__((address_space(1))) void*)g,
        (__attribute__((address_space(3))) void*)l, 16, 0, 0);
}

// lgkm-only barrier: seals LDS ops without draining VMEM (the whole point:
// in-flight global->VGPR prefetch loads survive the barrier).
#define SEAL() do {                                         \
    asm volatile("s_waitcnt lgkmcnt(0)" ::: "memory");      \
    __builtin_amdgcn_sched_barrier(0);                      \
    __builtin_amdgcn_s_barrier();                           \
    __builtin_amdgcn_sched_barrier(0);                      \
} while (0)

// ---- exact-enough GELU: A&S 7.1.26 erf, |err|<=1.5e-7 (invisible in bf16)
__device__ __forceinline__ float gelu_f(float v) {
    const float ax = fabsf(v) * 0.70710678118f;
    const float t  = __frcp_rn(1.0f + 0.3275911f * ax);
    float p = 1.061405429f;
    p = p * t - 1.453152027f;
    p = p * t + 1.421413741f;
    p = p * t - 0.284496736f;
    p = p * t + 0.254829592f;
    const float e = p * t * __expf(-ax * ax);
    const float erfv = (v >= 0.f) ? (1.0f - e) : (e - 1.0f);
    return 0.5f * v * (1.0f + erfv);
}

// =====================================================================
// GEMM:  out[M,N] = A[M,K] @ Bt[N,K]^T + bias
// MODE 0: store bf16   MODE 1: GELU then store bf16
// MODE 2: resid[M,N] (fp32) atomicAdd (split-K safe; bias only on z==0)
// 64x128 tile, BK=64, 4 waves 2x2 (wave = 32x64, acc[2][4]).
// bf16 path: REGISTER-STAGED double buffer. global_load->VGPR->ds_write.
//   Rationale (r4/r5/r6 post-mortems): with global_load_lds, EVERY barrier
//   scheme ends up draining the staging vmcnt before compute; with reg
//   staging the only vmcnt wait is the per-wave auto-wait at ds_write,
//   and the barrier is lgkmcnt-only -> tile t+2 loads stay in flight
//   across barriers. One s_barrier per K-iter (write buf^1 || read buf).
//   ds_write scatters freely -> swizzle on the WRITE side; global reads
//   are fully linear/coalesced. LDS 48 KB -> 3 blocks/CU.
// fp32 fallback: old single-buffer gld_lds loop (unused when ws fits).
// 1-D grid + XCD swizzle (T1).
// =====================================================================
template<typename WT, int MODE>
__global__ __launch_bounds__(256) void gemm_bt(
    const bf16* __restrict__ A, const WT* __restrict__ Bt,
    const float* __restrict__ bias, bf16* __restrict__ out,
    float* __restrict__ resid, int M, int N, int Kfull, int Ks)
{
    constexpr bool BF = (sizeof(WT) == 2);
    constexpr int NB  = BF ? 2 : 1;
    __shared__ __align__(16) bf16 lA[NB][64*64];    // 8 KB per buf
    __shared__ __align__(16) WT   lB[NB][128*64];   // 16 KB bf16 / 32 KB f32
    const int tid  = threadIdx.x;
    const int lane = tid & 63, wave = tid >> 6;
    const int lo = lane & 15, hi = lane >> 4;
    const int wm = wave & 1, wn = wave >> 1;

    // XCD swizzle: nblk % 8 == 0 for all call sites -> bijective
    const int nblk = gridDim.x;
    const int id2  = (blockIdx.x & 7) * (nblk >> 3) + (blockIdx.x >> 3);
    const int gx = M >> 6, gy = N >> 7;
    const int bx  = id2 % gx;
    const int byz = id2 / gx;
    const int by  = byz % gy;
    const int bz  = byz / gy;
    const int row0 = bx * 64, col0 = by * 128;
    const int k0base = bz * Ks;
    const int nt = Ks >> 6;

    f32x4 acc[2][4];
#pragma unroll
    for (int i = 0; i < 2; i++)
#pragma unroll
        for (int j = 0; j < 4; j++) acc[i][j] = (f32x4){0.f, 0.f, 0.f, 0.f};

    if constexpr (BF) {
        // ---- per-thread static chunk map (A: 2 chunks, B: 4 chunks) ----
        const bf16* pA[2]; int wAo[2];
#pragma unroll
        for (int r = 0; r < 2; ++r) {
            const int c = tid + r * 256;            // 0..511
            const int rw = c >> 3, kc = c & 7;
            pA[r]  = A + (size_t)(row0 + rw) * Kfull + k0base + kc * 8;
            wAo[r] = rw * 64 + (kc ^ (rw & 7)) * 8; // swizzled LDS offset
        }
        const bf16* pB[4]; int wBo[4];
#pragma unroll
        for (int r = 0; r < 4; ++r) {
            const int c = tid + r * 256;            // 0..1023
            const int rw = c >> 3, kc = c & 7;
            pB[r]  = (const bf16*)Bt + (size_t)(col0 + rw) * Kfull + k0base + kc * 8;
            wBo[r] = rw * 64 + (kc ^ (rw & 7)) * 8;
        }
        bf16x8 rA[2], rB[4];
        auto loadT = [&](int t) {
#pragma unroll
            for (int r = 0; r < 2; ++r) rA[r] = *(const bf16x8*)(pA[r] + t * 64);
#pragma unroll
            for (int r = 0; r < 4; ++r) rB[r] = *(const bf16x8*)(pB[r] + t * 64);
        };
        auto writeT = [&](int buf) {
#pragma unroll
            for (int r = 0; r < 2; ++r) *(bf16x8*)(&lA[buf][wAo[r]]) = rA[r];
#pragma unroll
            for (int r = 0; r < 4; ++r) *(bf16x8*)(&((bf16*)lB[buf])[wBo[r]]) = rB[r];
        };
        auto compute = [&](int buf) {
#pragma unroll 1
            for (int s = 0; s < 2; ++s) {
                bf16x8 af[2], bfr[4];
#pragma unroll
                for (int i = 0; i < 2; i++) {
                    const int rowA = wm * 32 + i * 16 + lo;
                    const int ca = (s * 4 + hi) ^ (lo & 7);
                    af[i] = *(const bf16x8*)(&lA[buf][rowA * 64 + ca * 8]);
                }
#pragma unroll
                for (int i = 0; i < 4; i++) {
                    const int rowB = wn * 64 + i * 16 + lo;
                    const int cc = (s * 4 + hi) ^ (lo & 7);
                    bfr[i] = *(const bf16x8*)(&((const bf16*)lB[buf])[rowB * 64 + cc * 8]);
                }
#pragma unroll
                for (int mi = 0; mi < 2; mi++)
#pragma unroll
                    for (int ni = 0; ni < 4; ni++)
                        acc[mi][ni] = __builtin_amdgcn_mfma_f32_16x16x32_bf16(
                            af[mi], bfr[ni], acc[mi][ni], 0, 0, 0);
            }
        };

        // prologue: tile0 -> LDS buf0; tile1 loads in flight
        loadT(0);
        writeT(0);                  // auto vmcnt wait on rA/rB here
        if (nt > 1) loadT(1);
        SEAL();
        int cur = 0;
#pragma unroll 1
        for (int t = 0; t < nt; ++t) {
            if (t + 1 < nt) {
                writeT(cur ^ 1);    // waits (auto, per-wave) tile t+1 regs
                if (t + 2 < nt) loadT(t + 2);   // stays in flight over SEAL
            }
            compute(cur);
            SEAL();
            cur ^= 1;
        }
    } else {
        // ---- fp32 fallback: single-buffer gld_lds, full-drain barriers ----
        for (int t = 0; t < nt; ++t) {
#pragma unroll
            for (int r = 0; r < 2; ++r) {
                const int cb    = r * 256 + wave * 64;
                const int chunk = cb + lane;
                const int rw = chunk >> 3, kc = chunk & 7;
                const int kcs = kc ^ (rw & 7);
                gld_lds16(A + (size_t)(row0 + rw) * Kfull + k0base + t * 64 + kcs * 8,
                          lA[0] + cb * 8);
            }
#pragma unroll
            for (int r = 0; r < 8; ++r) {
                const int cb    = r * 256 + wave * 64;
                const int chunk = cb + lane;
                const int rw = chunk >> 4, kc = chunk & 15;
                const int kcs = kc ^ ((rw & 7) << 1);
                gld_lds16(Bt + (size_t)(col0 + rw) * Kfull + k0base + t * 64 + kcs * 4,
                          (float*)lB[0] + cb * 4);
            }
            __syncthreads();
#pragma unroll 1
            for (int s = 0; s < 2; ++s) {
                bf16x8 af[2], bfr[4];
#pragma unroll
                for (int i = 0; i < 2; i++) {
                    const int rowA = wm * 32 + i * 16 + lo;
                    const int ca = (s * 4 + hi) ^ (lo & 7);
                    af[i] = *(const bf16x8*)(&lA[0][rowA * 64 + ca * 8]);
                }
#pragma unroll
                for (int i = 0; i < 4; i++) {
                    const int rowB = wn * 64 + i * 16 + lo;
                    const float* base = (const float*)lB[0] + rowB * 64;
                    const int c0 = (s * 8 + hi * 2) ^ ((lo & 7) << 1);
                    const f32x4 u0 = *(const f32x4*)(base + c0 * 4);
                    const f32x4 u1 = *(const f32x4*)(base + (c0 + 1) * 4);
                    bf16x8 f;
#pragma unroll
                    for (int e = 0; e < 4; e++) { f[e] = (bf16)u0[e]; f[4+e] = (bf16)u1[e]; }
                    bfr[i] = f;
                }
#pragma unroll
                for (int mi = 0; mi < 2; mi++)
#pragma unroll
                    for (int ni = 0; ni < 4; ni++)
                        acc[mi][ni] = __builtin_amdgcn_mfma_f32_16x16x32_bf16(
                            af[mi], bfr[ni], acc[mi][ni], 0, 0, 0);
            }
            __syncthreads();
        }
    }

    // epilogue: C/D layout col=lane&15, row=(lane>>4)*4+reg
    const float bscale = (bz == 0) ? 1.0f : 0.0f;
#pragma unroll
    for (int mi = 0; mi < 2; mi++) {
#pragma unroll
        for (int ni = 0; ni < 4; ni++) {
            const int gcol = col0 + wn * 64 + ni * 16 + lo;
            const float bv = bias[gcol] * bscale;
#pragma unroll
            for (int r = 0; r < 4; r++) {
                const int grow = row0 + wm * 32 + mi * 16 + hi * 4 + r;
                float v = acc[mi][ni][r] + bv;
                if (MODE == 1) v = gelu_f(v);
                if (MODE == 2) {
                    atomicAdd(&resid[(size_t)grow * N + gcol], v);
                } else {
                    out[(size_t)grow * N + gcol] = (bf16)v;
                }
            }
        }
    }
}

// =====================================================================
// fp32 -> bf16 bulk convert (weights), 8 elems/lane
// =====================================================================
__global__ __launch_bounds__(256) void cvt_k(
    const float* __restrict__ src, bf16* __restrict__ dst)
{
    const int i = (blockIdx.x * 256 + threadIdx.x) * 8;
    const f32x4 a = *(const f32x4*)(src + i);
    const f32x4 b = *(const f32x4*)(src + i + 4);
    bf16x8 o;
#pragma unroll
    for (int e = 0; e < 4; e++) { o[e] = (bf16)a[e]; o[4 + e] = (bf16)b[e]; }
    *(bf16x8*)(dst + i) = o;
}

// =====================================================================
// LayerNorm: fp32 in [T,768] -> OutT out [T,768]; one wave per token
// =====================================================================
template<typename OutT>
__global__ __launch_bounds__(256) void ln_k(
    const float* __restrict__ x, const float* __restrict__ g,
    const float* __restrict__ b, OutT* __restrict__ out)
{
    const int wave = threadIdx.x >> 6, lane = threadIdx.x & 63;
    const int t = blockIdx.x * 4 + wave;
    const float* row = x + (size_t)t * C_;
    f32x4 v[3];
    float s = 0.f, ss = 0.f;
#pragma unroll
    for (int j = 0; j < 3; j++) {
        v[j] = *(const f32x4*)(row + (j * 64 + lane) * 4);
#pragma unroll
        for (int e = 0; e < 4; e++) { s += v[j][e]; ss += v[j][e] * v[j][e]; }
    }
#pragma unroll
    for (int off = 32; off > 0; off >>= 1) {
        s  += __shfl_xor(s, off);
        ss += __shfl_xor(ss, off);
    }
    const float mu  = s * (1.f / 768.f);
    const float var = ss * (1.f / 768.f) - mu * mu;
    const float rs  = rsqrtf(var + 1e-5f);
    OutT* orow = out + (size_t)t * C_;
#pragma unroll
    for (int j = 0; j < 3; j++) {
        const f32x4 gv = *(const f32x4*)(g + (j * 64 + lane) * 4);
        const f32x4 bv = *(const f32x4*)(b + (j * 64 + lane) * 4);
#pragma unroll
        for (int e = 0; e < 4; e++)
            orow[(j * 64 + lane) * 4 + e] = (OutT)((v[j][e] - mu) * rs * gv[e] + bv[e]);
    }
}

// =====================================================================
// x + pos_x (fp32) -> fp32 residual stream
// =====================================================================
__global__ __launch_bounds__(256) void addpos_k(
    const float* __restrict__ x, const float* __restrict__ p, float* __restrict__ o)
{
    const int i = (blockIdx.x * 256 + threadIdx.x) * 4;
    const f32x4 xv = *(const f32x4*)(x + i);
    const f32x4 pv = *(const f32x4*)(p + i);
    f32x4 ov;
#pragma unroll
    for (int e = 0; e < 4; e++) ov[e] = xv[e] + pv[e];
    *(f32x4*)(o + i) = ov;
}

// =====================================================================
// Flash attention: qkv bf16 [4096, 2304] -> out bf16 [4096, 768]
// 1-D grid (768) + XCD swizzle; KVBLK=128; T13 defer-max. (round-3 ver)
// =====================================================================
#define SKD_ 72     // lK row stride  [key][d]
#define SVK_ 136    // lV row stride  [d][key]  (128+8)
#define SPK_ 136    // lP row stride  [q][key]
__global__ __launch_bounds__(256) void attn_k(
    const bf16* __restrict__ qkv, bf16* __restrict__ out)
{
    const int id2 = (blockIdx.x & 7) * 96 + (blockIdx.x >> 3);  // 768 blocks
    const int qt = id2 & 15;            // 0..15
    const int bh = id2 >> 4;            // 0..47
    const int b = bh / H_, h = bh % H_;
    const int lane = threadIdx.x & 63, wave = threadIdx.x >> 6;
    const int lo = lane & 15, hi = lane >> 4;

    __shared__ __align__(16) bf16 lK[128 * SKD_];     // 18432 B [key][d]
    __shared__ __align__(16) bf16 lV[64 * SVK_];      // 17408 B V^T [d][key]
    __shared__ __align__(16) bf16 lP[4][16 * SPK_];   // 17408 B per-wave P

    const size_t tokbase = (size_t)b * N_;

    // persistent Q A-fragments, pre-scaled by 1/sqrt(HD)=0.125 (exact pow2)
    const bf16* qptr = qkv + (tokbase + qt * 64 + wave * 16 + lo) * (3 * C_) + h * HD_;
    bf16x8 qf0 = *(const bf16x8*)(qptr + hi * 8);
    bf16x8 qf1 = *(const bf16x8*)(qptr + 32 + hi * 8);
#pragma unroll
    for (int e = 0; e < 8; e++) {
        qf0[e] = (bf16)((float)qf0[e] * 0.125f);
        qf1[e] = (bf16)((float)qf1[e] * 0.125f);
    }

    float m_r[4], l_r[4];
    f32x4 oacc[4];
#pragma unroll
    for (int r = 0; r < 4; r++) { m_r[r] = -1e30f; l_r[r] = 0.f; }
#pragma unroll
    for (int di = 0; di < 4; di++) oacc[di] = (f32x4){0.f, 0.f, 0.f, 0.f};

    for (int kt = 0; kt < 8; ++kt) {
        const int kb0 = kt * 128;
        // ---- K: vectorized [key][d] staging (128 keys x 8 chunks) ----
#pragma unroll
        for (int r = 0; r < 4; ++r) {
            const int chunk = r * 256 + threadIdx.x;     // 0..1023
            const int key = chunk >> 3, dc = chunk & 7;
            const bf16* kp = qkv + (tokbase + kb0 + key) * (3 * C_) + C_ + h * HD_ + dc * 8;
            *(bf16x8*)(lK + key * SKD_ + dc * 8) = *(const bf16x8*)kp;
        }
        // ---- V^T: transposed coalesced loads (lane d, 8 keys/chunk) ----
#pragma unroll
        for (int r = 0; r < 4; ++r) {
            const int chunk = r * 256 + threadIdx.x;     // 0..1023
            const int d = chunk & 63, kg = chunk >> 6;   // kg 0..15
            const bf16* vp = qkv + (tokbase + kb0 + kg * 8) * (3 * C_)
                           + 2 * C_ + h * HD_ + d;
            bf16x8 tv;
#pragma unroll
            for (int i = 0; i < 8; i++) tv[i] = vp[(size_t)i * (3 * C_)];
            *(bf16x8*)(lV + d * SVK_ + kg * 8) = tv;
        }
        __syncthreads();

        // ---- S = Q @ K^T (per wave: 16 q x 128 keys), already scaled ----
        f32x4 sacc[8];
#pragma unroll
        for (int kb = 0; kb < 8; kb++) {
            const bf16x8 b0 = *(const bf16x8*)(lK + (kb * 16 + lo) * SKD_ + hi * 8);
            const bf16x8 b1 = *(const bf16x8*)(lK + (kb * 16 + lo) * SKD_ + 32 + hi * 8);
            f32x4 a = (f32x4){0.f, 0.f, 0.f, 0.f};
            a = __builtin_amdgcn_mfma_f32_16x16x32_bf16(qf0, b0, a, 0, 0, 0);
            a = __builtin_amdgcn_mfma_f32_16x16x32_bf16(qf1, b1, a, 0, 0, 0);
            sacc[kb] = a;
        }

        // ---- online softmax, defer-max (row r = q row hi*4+r) ----
        float pm[4], mn[4], ts[4];
#pragma unroll
        for (int r = 0; r < 4; r++) {
            float a0 = fmaxf(fmaxf(sacc[0][r], sacc[1][r]),
                             fmaxf(sacc[2][r], sacc[3][r]));
            float a1 = fmaxf(fmaxf(sacc[4][r], sacc[5][r]),
                             fmaxf(sacc[6][r], sacc[7][r]));
            pm[r] = fmaxf(a0, a1);
            ts[r] = 0.f;
        }
        const int okd = (pm[0] <= m_r[0] + 8.f) && (pm[1] <= m_r[1] + 8.f)
                     && (pm[2] <= m_r[2] + 8.f) && (pm[3] <= m_r[3] + 8.f);
        const bool defer = __all(okd);
        if (defer) {
#pragma unroll
            for (int r = 0; r < 4; r++) mn[r] = m_r[r];
        } else {
#pragma unroll
            for (int r = 0; r < 4; r++) {
                float tm = pm[r];
#pragma unroll
                for (int off = 1; off < 16; off <<= 1)
                    tm = fmaxf(tm, __shfl_xor(tm, off));
                mn[r] = fmaxf(m_r[r], tm);
            }
        }
        // stream: exp -> wave-private lP -> partial sum
#pragma unroll
        for (int kb = 0; kb < 8; kb++)
#pragma unroll
            for (int r = 0; r < 4; r++) {
                const float p = __expf(sacc[kb][r] - mn[r]);
                lP[wave][(hi * 4 + r) * SPK_ + kb * 16 + lo] = (bf16)p;
                ts[r] += p;
            }
#pragma unroll
        for (int r = 0; r < 4; r++)
#pragma unroll
            for (int off = 1; off < 16; off <<= 1)
                ts[r] += __shfl_xor(ts[r], off);
        if (defer) {
#pragma unroll
            for (int r = 0; r < 4; r++) l_r[r] += ts[r];
        } else {
            float alpha[4];
#pragma unroll
            for (int r = 0; r < 4; r++) {
                alpha[r] = __expf(m_r[r] - mn[r]);
                l_r[r] = l_r[r] * alpha[r] + ts[r];
                m_r[r] = mn[r];
            }
#pragma unroll
            for (int di = 0; di < 4; di++)
#pragma unroll
                for (int r = 0; r < 4; r++) oacc[di][r] *= alpha[r];
        }

        // ---- PV: P A-frags (wave-private, no barrier needed) ----
        bf16x8 pa[4];
#pragma unroll
        for (int s = 0; s < 4; s++)
            pa[s] = *(const bf16x8*)(&lP[wave][lo * SPK_ + s * 32 + hi * 8]);
#pragma unroll
        for (int di = 0; di < 4; di++) {
#pragma unroll
            for (int s = 0; s < 4; s++) {
                const bf16x8 v = *(const bf16x8*)(lV + (di * 16 + lo) * SVK_ + s * 32 + hi * 8);
                oacc[di] = __builtin_amdgcn_mfma_f32_16x16x32_bf16(pa[s], v, oacc[di], 0, 0, 0);
            }
        }
        __syncthreads();
    }

    // ---- epilogue: O * (1/l) ----
    float il[4];
#pragma unroll
    for (int r = 0; r < 4; r++) il[r] = 1.0f / l_r[r];
#pragma unroll
    for (int di = 0; di < 4; di++)
#pragma unroll
        for (int r = 0; r < 4; r++) {
            const size_t tok = tokbase + qt * 64 + wave * 16 + hi * 4 + r;
            out[tok * C_ + h * HD_ + di * 16 + lo] = (bf16)(oacc[di][r] * il[r]);
        }
}

// =====================================================================
extern "C" void kernel_launch(void* const* d_in, const int* in_sizes, int n_in,
                              void* d_out, int out_size, void* d_ws, size_t ws_size,
                              hipStream_t stream)
{
    const float* x      = (const float*)d_in[0];
    const float* pos_x  = (const float*)d_in[1];
    const float* qkv_w  = (const float*)d_in[2];
    const float* qkv_b  = (const float*)d_in[3];
    const float* proj_w = (const float*)d_in[4];
    const float* proj_b = (const float*)d_in[5];
    const float* fc1_w  = (const float*)d_in[6];
    const float* fc1_b  = (const float*)d_in[7];
    const float* fc2_w  = (const float*)d_in[8];
    const float* fc2_b  = (const float*)d_in[9];
    const float* ln1_g  = (const float*)d_in[10];
    const float* ln1_b  = (const float*)d_in[11];
    const float* ln2_g  = (const float*)d_in[12];
    const float* ln2_b  = (const float*)d_in[13];
    const float* nf_g   = (const float*)d_in[14];
    const float* nf_b   = (const float*)d_in[15];

    char* ws = (char*)d_ws;
    float* xres  = (float*)(ws);                         // 12,582,912 B
    bf16* hbuf   = (bf16*)(ws + 12582912);               //  6,291,456
    bf16* qkvbuf = (bf16*)(ws + 18874368);               // 18,874,368
    bf16* attno  = (bf16*)(ws + 37748736);               //  6,291,456
    bf16* hid    = (bf16*)(ws + 44040192);               // 25,165,824 (end 69,206,016)
    bf16* wq     = (bf16*)(ws + 69206016);               // 42,467,328
    bf16* wp     = (bf16*)(ws + 111673344);              // 14,155,776
    bf16* w1     = (bf16*)(ws + 125829120);              // 56,623,104
    bf16* w2     = (bf16*)(ws + 182452224);              // 56,623,104 (end 239,075,328)
    const bool usebf16 = ws_size >= (size_t)239075328;

    addpos_k<<<T_ * C_ / 4 / 256, 256, 0, stream>>>(x, pos_x, xres);

    if (usebf16) {
        cvt_k<<<D_ * 3 * C_ * C_ / 2048, 256, 0, stream>>>(qkv_w, wq);
        cvt_k<<<D_ * C_ * C_ / 2048, 256, 0, stream>>>(proj_w, wp);
        cvt_k<<<D_ * FF_ * C_ / 2048, 256, 0, stream>>>(fc1_w, w1);
        cvt_k<<<D_ * C_ * FF_ / 2048, 256, 0, stream>>>(fc2_w, w2);
    }

    // 1-D grids, 64-row tiles (XCD swizzle decode inside kernels)
    const int g_qkv  = (T_/64) * ((3*C_)/128);       // 1152
    const int g_proj = (T_/64) * (C_/128) * 2;       // 768
    const int g_fc1  = (T_/64) * (FF_/128);          // 1536
    const int g_fc2  = (T_/64) * (C_/128) * 2;       // 768

    for (int L = 0; L < D_; ++L) {
        ln_k<bf16><<<T_ / 4, 256, 0, stream>>>(xres, ln1_g + L * C_, ln1_b + L * C_, hbuf);
        if (usebf16) {
            gemm_bt<bf16,0><<<g_qkv, 256, 0, stream>>>(
                hbuf, wq + (size_t)L * 3 * C_ * C_, qkv_b + (size_t)L * 3 * C_,
                qkvbuf, nullptr, T_, 3 * C_, C_, C_);
        } else {
            gemm_bt<float,0><<<g_qkv, 256, 0, stream>>>(
                hbuf, qkv_w + (size_t)L * 3 * C_ * C_, qkv_b + (size_t)L * 3 * C_,
                qkvbuf, nullptr, T_, 3 * C_, C_, C_);
        }
        attn_k<<<N_ / 64 * B_ * H_, 256, 0, stream>>>(qkvbuf, attno);
        if (usebf16) {
            gemm_bt<bf16,2><<<g_proj, 256, 0, stream>>>(
                attno, wp + (size_t)L * C_ * C_, proj_b + (size_t)L * C_,
                nullptr, xres, T_, C_, C_, C_ / 2);
        } else {
            gemm_bt<float,2><<<g_proj, 256, 0, stream>>>(
                attno, proj_w + (size_t)L * C_ * C_, proj_b + (size_t)L * C_,
                nullptr, xres, T_, C_, C_, C_ / 2);
        }
        ln_k<bf16><<<T_ / 4, 256, 0, stream>>>(xres, ln2_g + L * C_, ln2_b + L * C_, hbuf);
        if (usebf16) {
            gemm_bt<bf16,1><<<g_fc1, 256, 0, stream>>>(
                hbuf, w1 + (size_t)L * FF_ * C_, fc1_b + (size_t)L * FF_,
                hid, nullptr, T_, FF_, C_, C_);
            gemm_bt<bf16,2><<<g_fc2, 256, 0, stream>>>(
                hid, w2 + (size_t)L * C_ * FF_, fc2_b + (size_t)L * C_,
                nullptr, xres, T_, C_, FF_, FF_ / 2);
        } else {
            gemm_bt<float,1><<<g_fc1, 256, 0, stream>>>(
                hbuf, fc1_w + (size_t)L * FF_ * C_, fc1_b + (size_t)L * FF_,
                hid, nullptr, T_, FF_, C_, C_);
            gemm_bt<float,2><<<g_fc2, 256, 0, stream>>>(
                hid, fc2_w + (size_t)L * C_ * FF_, fc2_b + (size_t)L * C_,
                nullptr, xres, T_, C_, FF_, FF_ / 2);
        }
    }
    ln_k<float><<<T_ / 4, 256, 0, stream>>>(xres, nf_g, nf_b, (float*)d_out);
}

// Round 8
// 2410.244 us; speedup vs baseline: 1.2135x; 1.0422x over previous
//
#include <hip/hip_runtime.h>
#include <hip/hip_bf16.h>
#include <math.h>

typedef __bf16 bf16;
typedef __bf16 bf16x8 __attribute__((ext_vector_type(8)));
typedef __bf16 bf16x4 __attribute__((ext_vector_type(4)));
typedef float  f32x4  __attribute__((ext_vector_type(4)));

#define B_  4
#define N_  1024
#define C_  768
#define H_  12
#define HD_ 64
#define FF_ 3072
#define T_  (B_*N_)      // 4096 tokens
#define D_  12

// ---- async global->LDS, 16B per lane, wave-uniform LDS base ----
__device__ __forceinline__ void gld_lds16(const void* g, void* l) {
    __builtin_amdgcn_global_load_lds(
        (const __attribute__((address_space(1))) void*)g,
        (__attribute__((address_space(3))) void*)l, 16, 0, 0);
}

// lgkm-only barrier: seals LDS ops without draining VMEM (in-flight
// global->VGPR prefetch loads survive the barrier).
#define SEAL() do {                                         \
    asm volatile("s_waitcnt lgkmcnt(0)" ::: "memory");      \
    __builtin_amdgcn_sched_barrier(0);                      \
    __builtin_amdgcn_s_barrier();                           \
    __builtin_amdgcn_sched_barrier(0);                      \
} while (0)

// ---- exact-enough GELU: A&S 7.1.26 erf, |err|<=1.5e-7 (invisible in bf16)
__device__ __forceinline__ float gelu_f(float v) {
    const float ax = fabsf(v) * 0.70710678118f;
    const float t  = __frcp_rn(1.0f + 0.3275911f * ax);
    float p = 1.061405429f;
    p = p * t - 1.453152027f;
    p = p * t + 1.421413741f;
    p = p * t - 0.284496736f;
    p = p * t + 0.254829592f;
    const float e = p * t * __expf(-ax * ax);
    const float erfv = (v >= 0.f) ? (1.0f - e) : (e - 1.0f);
    return 0.5f * v * (1.0f + erfv);
}

// =====================================================================
// GEMM:  out[M,N] = A[M,K] @ Bt[N,K]^T + bias
// MODE 0: store bf16   MODE 1: GELU then store bf16
// MODE 2: resid[M,N] (fp32) atomicAdd (split-K safe; bias only on z==0)
// 64x128 tile, BK=64, 4 waves 2x2 (wave = 32x64, acc[2][4]).
// bf16 path: REGISTER-STAGED double buffer (r7, best), PLUS:
//  * L2-SUPERTILE XCD partition (r8): r3's fc1 FETCH=27MB vs 11MB ideal
//    showed A re-fetched ~4x -- old per-XCD chunk = 3 B-panels + FULL A
//    (6.9MB) > 4MB L2. New 4x2 supertile: each XCD owns 16 bx-rows x
//    gyz/2 col-tiles -> A-slice 1.57MB + B-slice <=2.36MB <= 3.9MB fits
//    L2 -> staging loads become ~200cy L2 hits instead of L3/HBM tail.
//  * compute BEFORE writeT: the writeT auto-vmcnt stall no longer delays
//    compute issue (r7 had compute after the stall in program order).
// fp32 fallback: single-buffer gld_lds loop (unused when ws fits).
// =====================================================================
template<typename WT, int MODE>
__global__ __launch_bounds__(256) void gemm_bt(
    const bf16* __restrict__ A, const WT* __restrict__ Bt,
    const float* __restrict__ bias, bf16* __restrict__ out,
    float* __restrict__ resid, int M, int N, int Kfull, int Ks)
{
    constexpr bool BF = (sizeof(WT) == 2);
    constexpr int NB  = BF ? 2 : 1;
    __shared__ __align__(16) bf16 lA[NB][64*64];    // 8 KB per buf
    __shared__ __align__(16) WT   lB[NB][128*64];   // 16 KB bf16 / 32 KB f32
    const int tid  = threadIdx.x;
    const int lane = tid & 63, wave = tid >> 6;
    const int lo = lane & 15, hi = lane >> 4;
    const int wm = wave & 1, wn = wave >> 1;

    // ---- L2-supertile decode: XCD x owns supertile (x&3, x>>2) of the
    // 4x2 split of (gx, gyz).  gx=64 always (M=4096); gyz even for all
    // call sites (18,24,12,12).  Bijective: w in [0, gx*gyz/8).
    const int xcd = blockIdx.x & 7;
    const int w   = blockIdx.x >> 3;
    const int gy  = N >> 7;
    const int gz  = Kfull / Ks;
    const int gyz = gy * gz;
    const int bx  = (xcd & 3) * 16 + (w & 15);
    const int byz = (xcd >> 2) * (gyz >> 1) + (w >> 4);
    const int by  = byz % gy;
    const int bz  = byz / gy;
    const int row0 = bx * 64, col0 = by * 128;
    const int k0base = bz * Ks;
    const int nt = Ks >> 6;

    f32x4 acc[2][4];
#pragma unroll
    for (int i = 0; i < 2; i++)
#pragma unroll
        for (int j = 0; j < 4; j++) acc[i][j] = (f32x4){0.f, 0.f, 0.f, 0.f};

    if constexpr (BF) {
        // ---- per-thread static chunk map (A: 2 chunks, B: 4 chunks) ----
        const bf16* pA[2]; int wAo[2];
#pragma unroll
        for (int r = 0; r < 2; ++r) {
            const int c = tid + r * 256;            // 0..511
            const int rw = c >> 3, kc = c & 7;
            pA[r]  = A + (size_t)(row0 + rw) * Kfull + k0base + kc * 8;
            wAo[r] = rw * 64 + (kc ^ (rw & 7)) * 8; // swizzled LDS offset
        }
        const bf16* pB[4]; int wBo[4];
#pragma unroll
        for (int r = 0; r < 4; ++r) {
            const int c = tid + r * 256;            // 0..1023
            const int rw = c >> 3, kc = c & 7;
            pB[r]  = (const bf16*)Bt + (size_t)(col0 + rw) * Kfull + k0base + kc * 8;
            wBo[r] = rw * 64 + (kc ^ (rw & 7)) * 8;
        }
        bf16x8 rA[2], rB[4];
        auto loadT = [&](int t) {
#pragma unroll
            for (int r = 0; r < 2; ++r) rA[r] = *(const bf16x8*)(pA[r] + t * 64);
#pragma unroll
            for (int r = 0; r < 4; ++r) rB[r] = *(const bf16x8*)(pB[r] + t * 64);
        };
        auto writeT = [&](int buf) {
#pragma unroll
            for (int r = 0; r < 2; ++r) *(bf16x8*)(&lA[buf][wAo[r]]) = rA[r];
#pragma unroll
            for (int r = 0; r < 4; ++r) *(bf16x8*)(&((bf16*)lB[buf])[wBo[r]]) = rB[r];
        };
        auto compute = [&](int buf) {
#pragma unroll 1
            for (int s = 0; s < 2; ++s) {
                bf16x8 af[2], bfr[4];
#pragma unroll
                for (int i = 0; i < 2; i++) {
                    const int rowA = wm * 32 + i * 16 + lo;
                    const int ca = (s * 4 + hi) ^ (lo & 7);
                    af[i] = *(const bf16x8*)(&lA[buf][rowA * 64 + ca * 8]);
                }
#pragma unroll
                for (int i = 0; i < 4; i++) {
                    const int rowB = wn * 64 + i * 16 + lo;
                    const int cc = (s * 4 + hi) ^ (lo & 7);
                    bfr[i] = *(const bf16x8*)(&((const bf16*)lB[buf])[rowB * 64 + cc * 8]);
                }
#pragma unroll
                for (int mi = 0; mi < 2; mi++)
#pragma unroll
                    for (int ni = 0; ni < 4; ni++)
                        acc[mi][ni] = __builtin_amdgcn_mfma_f32_16x16x32_bf16(
                            af[mi], bfr[ni], acc[mi][ni], 0, 0, 0);
            }
        };

        // prologue: tile0 -> LDS buf0; tile1 loads in flight
        loadT(0);
        writeT(0);                  // auto vmcnt wait on rA/rB here
        if (nt > 1) loadT(1);
        SEAL();
        int cur = 0;
#pragma unroll 1
        for (int t = 0; t < nt; ++t) {
            compute(cur);           // issues ds_read+MFMA before any stall
            if (t + 1 < nt) {
                writeT(cur ^ 1);    // waits (auto, per-wave) tile t+1 regs
                if (t + 2 < nt) loadT(t + 2);   // stays in flight over SEAL
            }
            SEAL();
            cur ^= 1;
        }
    } else {
        // ---- fp32 fallback: single-buffer gld_lds, full-drain barriers ----
        for (int t = 0; t < nt; ++t) {
#pragma unroll
            for (int r = 0; r < 2; ++r) {
                const int cb    = r * 256 + wave * 64;
                const int chunk = cb + lane;
                const int rw = chunk >> 3, kc = chunk & 7;
                const int kcs = kc ^ (rw & 7);
                gld_lds16(A + (size_t)(row0 + rw) * Kfull + k0base + t * 64 + kcs * 8,
                          lA[0] + cb * 8);
            }
#pragma unroll
            for (int r = 0; r < 8; ++r) {
                const int cb    = r * 256 + wave * 64;
                const int chunk = cb + lane;
                const int rw = chunk >> 4, kc = chunk & 15;
                const int kcs = kc ^ ((rw & 7) << 1);
                gld_lds16(Bt + (size_t)(col0 + rw) * Kfull + k0base + t * 64 + kcs * 4,
                          (float*)lB[0] + cb * 4);
            }
            __syncthreads();
#pragma unroll 1
            for (int s = 0; s < 2; ++s) {
                bf16x8 af[2], bfr[4];
#pragma unroll
                for (int i = 0; i < 2; i++) {
                    const int rowA = wm * 32 + i * 16 + lo;
                    const int ca = (s * 4 + hi) ^ (lo & 7);
                    af[i] = *(const bf16x8*)(&lA[0][rowA * 64 + ca * 8]);
                }
#pragma unroll
                for (int i = 0; i < 4; i++) {
                    const int rowB = wn * 64 + i * 16 + lo;
                    const float* base = (const float*)lB[0] + rowB * 64;
                    const int c0 = (s * 8 + hi * 2) ^ ((lo & 7) << 1);
                    const f32x4 u0 = *(const f32x4*)(base + c0 * 4);
                    const f32x4 u1 = *(const f32x4*)(base + (c0 + 1) * 4);
                    bf16x8 f;
#pragma unroll
                    for (int e = 0; e < 4; e++) { f[e] = (bf16)u0[e]; f[4+e] = (bf16)u1[e]; }
                    bfr[i] = f;
                }
#pragma unroll
                for (int mi = 0; mi < 2; mi++)
#pragma unroll
                    for (int ni = 0; ni < 4; ni++)
                        acc[mi][ni] = __builtin_amdgcn_mfma_f32_16x16x32_bf16(
                            af[mi], bfr[ni], acc[mi][ni], 0, 0, 0);
            }
            __syncthreads();
        }
    }

    // epilogue: C/D layout col=lane&15, row=(lane>>4)*4+reg
    const float bscale = (bz == 0) ? 1.0f : 0.0f;
#pragma unroll
    for (int mi = 0; mi < 2; mi++) {
#pragma unroll
        for (int ni = 0; ni < 4; ni++) {
            const int gcol = col0 + wn * 64 + ni * 16 + lo;
            const float bv = bias[gcol] * bscale;
#pragma unroll
            for (int r = 0; r < 4; r++) {
                const int grow = row0 + wm * 32 + mi * 16 + hi * 4 + r;
                float v = acc[mi][ni][r] + bv;
                if (MODE == 1) v = gelu_f(v);
                if (MODE == 2) {
                    atomicAdd(&resid[(size_t)grow * N + gcol], v);
                } else {
                    out[(size_t)grow * N + gcol] = (bf16)v;
                }
            }
        }
    }
}

// =====================================================================
// fp32 -> bf16 bulk convert (weights), 8 elems/lane
// =====================================================================
__global__ __launch_bounds__(256) void cvt_k(
    const float* __restrict__ src, bf16* __restrict__ dst)
{
    const int i = (blockIdx.x * 256 + threadIdx.x) * 8;
    const f32x4 a = *(const f32x4*)(src + i);
    const f32x4 b = *(const f32x4*)(src + i + 4);
    bf16x8 o;
#pragma unroll
    for (int e = 0; e < 4; e++) { o[e] = (bf16)a[e]; o[4 + e] = (bf16)b[e]; }
    *(bf16x8*)(dst + i) = o;
}

// =====================================================================
// LayerNorm: fp32 in [T,768] -> OutT out [T,768]; one wave per token
// =====================================================================
template<typename OutT>
__global__ __launch_bounds__(256) void ln_k(
    const float* __restrict__ x, const float* __restrict__ g,
    const float* __restrict__ b, OutT* __restrict__ out)
{
    const int wave = threadIdx.x >> 6, lane = threadIdx.x & 63;
    const int t = blockIdx.x * 4 + wave;
    const float* row = x + (size_t)t * C_;
    f32x4 v[3];
    float s = 0.f, ss = 0.f;
#pragma unroll
    for (int j = 0; j < 3; j++) {
        v[j] = *(const f32x4*)(row + (j * 64 + lane) * 4);
#pragma unroll
        for (int e = 0; e < 4; e++) { s += v[j][e]; ss += v[j][e] * v[j][e]; }
    }
#pragma unroll
    for (int off = 32; off > 0; off >>= 1) {
        s  += __shfl_xor(s, off);
        ss += __shfl_xor(ss, off);
    }
    const float mu  = s * (1.f / 768.f);
    const float var = ss * (1.f / 768.f) - mu * mu;
    const float rs  = rsqrtf(var + 1e-5f);
    OutT* orow = out + (size_t)t * C_;
#pragma unroll
    for (int j = 0; j < 3; j++) {
        const f32x4 gv = *(const f32x4*)(g + (j * 64 + lane) * 4);
        const f32x4 bv = *(const f32x4*)(b + (j * 64 + lane) * 4);
#pragma unroll
        for (int e = 0; e < 4; e++)
            orow[(j * 64 + lane) * 4 + e] = (OutT)((v[j][e] - mu) * rs * gv[e] + bv[e]);
    }
}

// =====================================================================
// x + pos_x (fp32) -> fp32 residual stream
// =====================================================================
__global__ __launch_bounds__(256) void addpos_k(
    const float* __restrict__ x, const float* __restrict__ p, float* __restrict__ o)
{
    const int i = (blockIdx.x * 256 + threadIdx.x) * 4;
    const f32x4 xv = *(const f32x4*)(x + i);
    const f32x4 pv = *(const f32x4*)(p + i);
    f32x4 ov;
#pragma unroll
    for (int e = 0; e < 4; e++) ov[e] = xv[e] + pv[e];
    *(f32x4*)(o + i) = ov;
}

// =====================================================================
// Flash attention: qkv bf16 [4096, 2304] -> out bf16 [4096, 768]
// 1-D grid (768) + XCD swizzle; KVBLK=128; T13 defer-max.
// NEW (r8): l-sum via MFMA against all-ones B fragment -- replaces the
// 16-shfl sum tree + 32 serial adds (~150cy LDS/VALU) with 4 MFMAs.
// D[q][j] = sum_k P[q][k] for every j -> each lane gets its 4 rows'
// sums directly in the l_r register mapping. Sums the same bf16 P
// that PV consumes (error << current absmax).
// =====================================================================
#define SKD_ 72     // lK row stride  [key][d]
#define SVK_ 136    // lV row stride  [d][key]  (128+8)
#define SPK_ 136    // lP row stride  [q][key]
__global__ __launch_bounds__(256) void attn_k(
    const bf16* __restrict__ qkv, bf16* __restrict__ out)
{
    const int id2 = (blockIdx.x & 7) * 96 + (blockIdx.x >> 3);  // 768 blocks
    const int qt = id2 & 15;            // 0..15
    const int bh = id2 >> 4;            // 0..47
    const int b = bh / H_, h = bh % H_;
    const int lane = threadIdx.x & 63, wave = threadIdx.x >> 6;
    const int lo = lane & 15, hi = lane >> 4;

    __shared__ __align__(16) bf16 lK[128 * SKD_];     // 18432 B [key][d]
    __shared__ __align__(16) bf16 lV[64 * SVK_];      // 17408 B V^T [d][key]
    __shared__ __align__(16) bf16 lP[4][16 * SPK_];   // 17408 B per-wave P

    const size_t tokbase = (size_t)b * N_;

    // persistent Q A-fragments, pre-scaled by 1/sqrt(HD)=0.125 (exact pow2)
    const bf16* qptr = qkv + (tokbase + qt * 64 + wave * 16 + lo) * (3 * C_) + h * HD_;
    bf16x8 qf0 = *(const bf16x8*)(qptr + hi * 8);
    bf16x8 qf1 = *(const bf16x8*)(qptr + 32 + hi * 8);
#pragma unroll
    for (int e = 0; e < 8; e++) {
        qf0[e] = (bf16)((float)qf0[e] * 0.125f);
        qf1[e] = (bf16)((float)qf1[e] * 0.125f);
    }
    bf16x8 onesf;
#pragma unroll
    for (int e = 0; e < 8; e++) onesf[e] = (bf16)1.0f;

    float m_r[4], l_r[4];
    f32x4 oacc[4];
#pragma unroll
    for (int r = 0; r < 4; r++) { m_r[r] = -1e30f; l_r[r] = 0.f; }
#pragma unroll
    for (int di = 0; di < 4; di++) oacc[di] = (f32x4){0.f, 0.f, 0.f, 0.f};

    for (int kt = 0; kt < 8; ++kt) {
        const int kb0 = kt * 128;
        // ---- K: vectorized [key][d] staging (128 keys x 8 chunks) ----
#pragma unroll
        for (int r = 0; r < 4; ++r) {
            const int chunk = r * 256 + threadIdx.x;     // 0..1023
            const int key = chunk >> 3, dc = chunk & 7;
            const bf16* kp = qkv + (tokbase + kb0 + key) * (3 * C_) + C_ + h * HD_ + dc * 8;
            *(bf16x8*)(lK + key * SKD_ + dc * 8) = *(const bf16x8*)kp;
        }
        // ---- V^T: transposed coalesced loads (lane d, 8 keys/chunk) ----
#pragma unroll
        for (int r = 0; r < 4; ++r) {
            const int chunk = r * 256 + threadIdx.x;     // 0..1023
            const int d = chunk & 63, kg = chunk >> 6;   // kg 0..15
            const bf16* vp = qkv + (tokbase + kb0 + kg * 8) * (3 * C_)
                           + 2 * C_ + h * HD_ + d;
            bf16x8 tv;
#pragma unroll
            for (int i = 0; i < 8; i++) tv[i] = vp[(size_t)i * (3 * C_)];
            *(bf16x8*)(lV + d * SVK_ + kg * 8) = tv;
        }
        __syncthreads();

        // ---- S = Q @ K^T (per wave: 16 q x 128 keys), already scaled ----
        f32x4 sacc[8];
#pragma unroll
        for (int kb = 0; kb < 8; kb++) {
            const bf16x8 b0 = *(const bf16x8*)(lK + (kb * 16 + lo) * SKD_ + hi * 8);
            const bf16x8 b1 = *(const bf16x8*)(lK + (kb * 16 + lo) * SKD_ + 32 + hi * 8);
            f32x4 a = (f32x4){0.f, 0.f, 0.f, 0.f};
            a = __builtin_amdgcn_mfma_f32_16x16x32_bf16(qf0, b0, a, 0, 0, 0);
            a = __builtin_amdgcn_mfma_f32_16x16x32_bf16(qf1, b1, a, 0, 0, 0);
            sacc[kb] = a;
        }

        // ---- online softmax, defer-max (row r = q row hi*4+r) ----
        float pm[4], mn[4];
#pragma unroll
        for (int r = 0; r < 4; r++) {
            float a0 = fmaxf(fmaxf(sacc[0][r], sacc[1][r]),
                             fmaxf(sacc[2][r], sacc[3][r]));
            float a1 = fmaxf(fmaxf(sacc[4][r], sacc[5][r]),
                             fmaxf(sacc[6][r], sacc[7][r]));
            pm[r] = fmaxf(a0, a1);
        }
        const int okd = (pm[0] <= m_r[0] + 8.f) && (pm[1] <= m_r[1] + 8.f)
                     && (pm[2] <= m_r[2] + 8.f) && (pm[3] <= m_r[3] + 8.f);
        const bool defer = __all(okd);
        if (defer) {
#pragma unroll
            for (int r = 0; r < 4; r++) mn[r] = m_r[r];
        } else {
#pragma unroll
            for (int r = 0; r < 4; r++) {
                float tm = pm[r];
#pragma unroll
                for (int off = 1; off < 16; off <<= 1)
                    tm = fmaxf(tm, __shfl_xor(tm, off));
                mn[r] = fmaxf(m_r[r], tm);
            }
        }
        // exp -> wave-private lP (no running scalar sum; MFMA does it)
#pragma unroll
        for (int kb = 0; kb < 8; kb++)
#pragma unroll
            for (int r = 0; r < 4; r++) {
                const float p = __expf(sacc[kb][r] - mn[r]);
                lP[wave][(hi * 4 + r) * SPK_ + kb * 16 + lo] = (bf16)p;
            }

        // ---- P A-frags (wave-private; compiler inserts lgkm wait) ----
        bf16x8 pa[4];
#pragma unroll
        for (int s = 0; s < 4; s++)
            pa[s] = *(const bf16x8*)(&lP[wave][lo * SPK_ + s * 32 + hi * 8]);

        // ---- l-sum via MFMA: ls[r] = sum_k P[row hi*4+r][k] ----
        f32x4 ls = (f32x4){0.f, 0.f, 0.f, 0.f};
#pragma unroll
        for (int s = 0; s < 4; s++)
            ls = __builtin_amdgcn_mfma_f32_16x16x32_bf16(pa[s], onesf, ls, 0, 0, 0);

        if (defer) {
#pragma unroll
            for (int r = 0; r < 4; r++) l_r[r] += ls[r];
        } else {
            float alpha[4];
#pragma unroll
            for (int r = 0; r < 4; r++) {
                alpha[r] = __expf(m_r[r] - mn[r]);
                l_r[r] = l_r[r] * alpha[r] + ls[r];
                m_r[r] = mn[r];
            }
#pragma unroll
            for (int di = 0; di < 4; di++)
#pragma unroll
                for (int r = 0; r < 4; r++) oacc[di][r] *= alpha[r];
        }

        // ---- PV ----
#pragma unroll
        for (int di = 0; di < 4; di++) {
#pragma unroll
            for (int s = 0; s < 4; s++) {
                const bf16x8 v = *(const bf16x8*)(lV + (di * 16 + lo) * SVK_ + s * 32 + hi * 8);
                oacc[di] = __builtin_amdgcn_mfma_f32_16x16x32_bf16(pa[s], v, oacc[di], 0, 0, 0);
            }
        }
        __syncthreads();
    }

    // ---- epilogue: O * (1/l) ----
    float il[4];
#pragma unroll
    for (int r = 0; r < 4; r++) il[r] = 1.0f / l_r[r];
#pragma unroll
    for (int di = 0; di < 4; di++)
#pragma unroll
        for (int r = 0; r < 4; r++) {
            const size_t tok = tokbase + qt * 64 + wave * 16 + hi * 4 + r;
            out[tok * C_ + h * HD_ + di * 16 + lo] = (bf16)(oacc[di][r] * il[r]);
        }
}

// =====================================================================
extern "C" void kernel_launch(void* const* d_in, const int* in_sizes, int n_in,
                              void* d_out, int out_size, void* d_ws, size_t ws_size,
                              hipStream_t stream)
{
    const float* x      = (const float*)d_in[0];
    const float* pos_x  = (const float*)d_in[1];
    const float* qkv_w  = (const float*)d_in[2];
    const float* qkv_b  = (const float*)d_in[3];
    const float* proj_w = (const float*)d_in[4];
    const float* proj_b = (const float*)d_in[5];
    const float* fc1_w  = (const float*)d_in[6];
    const float* fc1_b  = (const float*)d_in[7];
    const float* fc2_w  = (const float*)d_in[8];
    const float* fc2_b  = (const float*)d_in[9];
    const float* ln1_g  = (const float*)d_in[10];
    const float* ln1_b  = (const float*)d_in[11];
    const float* ln2_g  = (const float*)d_in[12];
    const float* ln2_b  = (const float*)d_in[13];
    const float* nf_g   = (const float*)d_in[14];
    const float* nf_b   = (const float*)d_in[15];

    char* ws = (char*)d_ws;
    float* xres  = (float*)(ws);                         // 12,582,912 B
    bf16* hbuf   = (bf16*)(ws + 12582912);               //  6,291,456
    bf16* qkvbuf = (bf16*)(ws + 18874368);               // 18,874,368
    bf16* attno  = (bf16*)(ws + 37748736);               //  6,291,456
    bf16* hid    = (bf16*)(ws + 44040192);               // 25,165,824 (end 69,206,016)
    bf16* wq     = (bf16*)(ws + 69206016);               // 42,467,328
    bf16* wp     = (bf16*)(ws + 111673344);              // 14,155,776
    bf16* w1     = (bf16*)(ws + 125829120);              // 56,623,104
    bf16* w2     = (bf16*)(ws + 182452224);              // 56,623,104 (end 239,075,328)
    const bool usebf16 = ws_size >= (size_t)239075328;

    addpos_k<<<T_ * C_ / 4 / 256, 256, 0, stream>>>(x, pos_x, xres);

    if (usebf16) {
        cvt_k<<<D_ * 3 * C_ * C_ / 2048, 256, 0, stream>>>(qkv_w, wq);
        cvt_k<<<D_ * C_ * C_ / 2048, 256, 0, stream>>>(proj_w, wp);
        cvt_k<<<D_ * FF_ * C_ / 2048, 256, 0, stream>>>(fc1_w, w1);
        cvt_k<<<D_ * C_ * FF_ / 2048, 256, 0, stream>>>(fc2_w, w2);
    }

    // 1-D grids, 64-row tiles (L2-supertile decode inside kernels)
    const int g_qkv  = (T_/64) * ((3*C_)/128);       // 1152
    const int g_proj = (T_/64) * (C_/128) * 2;       // 768
    const int g_fc1  = (T_/64) * (FF_/128);          // 1536
    const int g_fc2  = (T_/64) * (C_/128) * 2;       // 768

    for (int L = 0; L < D_; ++L) {
        ln_k<bf16><<<T_ / 4, 256, 0, stream>>>(xres, ln1_g + L * C_, ln1_b + L * C_, hbuf);
        if (usebf16) {
            gemm_bt<bf16,0><<<g_qkv, 256, 0, stream>>>(
                hbuf, wq + (size_t)L * 3 * C_ * C_, qkv_b + (size_t)L * 3 * C_,
                qkvbuf, nullptr, T_, 3 * C_, C_, C_);
        } else {
            gemm_bt<float,0><<<g_qkv, 256, 0, stream>>>(
                hbuf, qkv_w + (size_t)L * 3 * C_ * C_, qkv_b + (size_t)L * 3 * C_,
                qkvbuf, nullptr, T_, 3 * C_, C_, C_);
        }
        attn_k<<<N_ / 64 * B_ * H_, 256, 0, stream>>>(qkvbuf, attno);
        if (usebf16) {
            gemm_bt<bf16,2><<<g_proj, 256, 0, stream>>>(
                attno, wp + (size_t)L * C_ * C_, proj_b + (size_t)L * C_,
                nullptr, xres, T_, C_, C_, C_ / 2);
        } else {
            gemm_bt<float,2><<<g_proj, 256, 0, stream>>>(
                attno, proj_w + (size_t)L * C_ * C_, proj_b + (size_t)L * C_,
                nullptr, xres, T_, C_, C_, C_ / 2);
        }
        ln_k<bf16><<<T_ / 4, 256, 0, stream>>>(xres, ln2_g + L * C_, ln2_b + L * C_, hbuf);
        if (usebf16) {
            gemm_bt<bf16,1><<<g_fc1, 256, 0, stream>>>(
                hbuf, w1 + (size_t)L * FF_ * C_, fc1_b + (size_t)L * FF_,
                hid, nullptr, T_, FF_, C_, C_);
            gemm_bt<bf16,2><<<g_fc2, 256, 0, stream>>>(
                hid, w2 + (size_t)L * C_ * FF_, fc2_b + (size_t)L * C_,
                nullptr, xres, T_, C_, FF_, FF_ / 2);
        } else {
            gemm_bt<float,1><<<g_fc1, 256, 0, stream>>>(
                hbuf, fc1_w + (size_t)L * FF_ * C_, fc1_b + (size_t)L * FF_,
                hid, nullptr, T_, FF_, C_, C_);
            gemm_bt<float,2><<<g_fc2, 256, 0, stream>>>(
                hid, fc2_w + (size_t)L * C_ * FF_, fc2_b + (size_t)L * C_,
                nullptr, xres, T_, C_, FF_, FF_ / 2);
        }
    }
    ln_k<float><<<T_ / 4, 256, 0, stream>>>(xres, nf_g, nf_b, (float*)d_out);
}